// Round 6
// baseline (550.595 us; speedup 1.0000x reference)
//
#include <hip/hip_runtime.h>

// ---------------------------------------------------------------------------
// PrimitiveDecoder: 4-layer LSTM (NH=1024), T=101 steps, tiny head.
//
// Round-11 = R10 (measured 349us dispatch, best) minus intra-block
// orchestration overhead. Poll protocol / replica layout / lag-3 head /
// expf / fused head load: identical to R10. Two structural deltas:
//  1. SINGLE barrier per step via double-buffered vh4[2][256]:
//     iter t = { stage(t) into vh4[t&1]; barrier; dot from vh4[t&1];
//     reduce; nonlin; publish }. Correctness: write(t, buf b) happens
//     after barrier(t-1), which all waves pass only after their
//     compute(t-2) reads of buf b. Staging waves also start polling t+1
//     right after compute(t) -- earlier poll issue than R10's
//     post-barrier2 position.
//  2. Buddy-pair publish: wave wv in {4..7} publishes its own pair AND
//     wave (wv-4)'s pair (16-lane scatter: 8 replicas x 2 dwords), via a
//     4-entry SENT-gated hout handoff. Publish gates on max-of-2 waves
//     instead of R10's max-of-8 + wave7 relay. Waves 0-3 STILL never
//     global-store (R5 invariant: staging polls' vmcnt(0) waits only on
//     their own loads).
// Ledger: protocol restructures regress (R7 +66us, R8 +478us, R9 +155us);
// serial-chain shortening wins (R10 -57us). This round shortens chains.
// ---------------------------------------------------------------------------

#define TT    101
#define NBLK  256
#define NTH   512
#define NREP  8
#define SLAB_U32 512                               // 1024 f16 per replica
#define HB16_BYTES (4 * TT * NREP * SLAB_U32 * 4)  // 6,615,040 B
#define OUT_PROBS 6464
#define OUT_SAMP  6666
#define SENT 0xFFFFFFFFu

typedef _Float16 h2 __attribute__((ext_vector_type(2)));

__device__ __forceinline__ h2 mkh2(float a, float b) {
    h2 r; r.x = (_Float16)a; r.y = (_Float16)b; return r;
}
__device__ __forceinline__ unsigned pack2(float a, float b) {
    return __builtin_bit_cast(unsigned, mkh2(a, b));
}
__device__ __forceinline__ h2 as_h2(unsigned u) { return __builtin_bit_cast(h2, u); }

#if __has_builtin(__builtin_amdgcn_fdot2)
__device__ __forceinline__ float fdot2(h2 a, h2 b, float c) {
    return __builtin_amdgcn_fdot2(a, b, c, false);
}
#else
__device__ __forceinline__ float fdot2(h2 a, h2 b, float c) {
    return fmaf((float)a.x, (float)b.x, fmaf((float)a.y, (float)b.y, c));
}
#endif

// 16B cache-bypass load (coherent); waitcnt inside so result regs valid.
__device__ __forceinline__ uint4 load16_bypass(const uint4* p) {
    uint4 r;
    asm volatile("global_load_dwordx4 %0, %1, off sc0 sc1\n\ts_waitcnt vmcnt(0)"
                 : "=v"(r) : "v"(p) : "memory");
    return r;
}
__device__ __forceinline__ void store4_bypass(unsigned* p, unsigned v) {
    asm volatile("global_store_dword %0, %1, off sc0 sc1" :: "v"(p), "v"(v) : "memory");
}
// Two 16B cache-bypass loads back-to-back, ONE vmcnt(0): 1 RT not 2.
__device__ __forceinline__ void load32_bypass2(const uint4* p0, const uint4* p1,
                                               uint4& r0, uint4& r1) {
    asm volatile("global_load_dwordx4 %0, %2, off sc0 sc1\n\t"
                 "global_load_dwordx4 %1, %3, off sc0 sc1\n\t"
                 "s_waitcnt vmcnt(0)"
                 : "=&v"(r0), "=&v"(r1) : "v"(p0), "v"(p1) : "memory");
}
// R5's proven serial poll: load, check, sleep-retry.
__device__ __forceinline__ uint4 poll16(const uint4* p) {
    uint4 r = load16_bypass(p);
    while (r.x == SENT || r.y == SENT || r.z == SENT || r.w == SENT) {
        __builtin_amdgcn_s_sleep(1);
        r = load16_bypass(p);
    }
    return r;
}
__device__ __forceinline__ bool stale(const uint4& u) {
    return (u.x == SENT) | (u.y == SENT) | (u.z == SENT) | (u.w == SENT);
}

// rocPRIM-style full-wave (64) sum via DPP; total broadcast via readlane(63).
__device__ __forceinline__ float wave_sum(float x) {
    int v;
    v = __builtin_amdgcn_update_dpp(0, __builtin_bit_cast(int, x), 0x111, 0xf, 0xf, false);
    x += __builtin_bit_cast(float, v);                                  // row_shr:1
    v = __builtin_amdgcn_update_dpp(0, __builtin_bit_cast(int, x), 0x112, 0xf, 0xf, false);
    x += __builtin_bit_cast(float, v);                                  // row_shr:2
    v = __builtin_amdgcn_update_dpp(0, __builtin_bit_cast(int, x), 0x114, 0xf, 0xe, false);
    x += __builtin_bit_cast(float, v);                                  // row_shr:4
    v = __builtin_amdgcn_update_dpp(0, __builtin_bit_cast(int, x), 0x118, 0xf, 0xc, false);
    x += __builtin_bit_cast(float, v);                                  // row_shr:8
    v = __builtin_amdgcn_update_dpp(0, __builtin_bit_cast(int, x), 0x142, 0xa, 0xf, false);
    x += __builtin_bit_cast(float, v);                                  // row_bcast:15
    v = __builtin_amdgcn_update_dpp(0, __builtin_bit_cast(int, x), 0x143, 0xc, 0xf, false);
    x += __builtin_bit_cast(float, v);                                  // row_bcast:31
    return __builtin_bit_cast(float, __builtin_amdgcn_readlane(__builtin_bit_cast(int, x), 63));
}

// fast transcendentals (v_exp_f32-based); validated R7-R10: absmax equal.
__device__ __forceinline__ float sigm(float x)   { return 1.f / (1.f + __expf(-x)); }
__device__ __forceinline__ float tanh_f(float x) { return 1.f - 2.f / (1.f + __expf(x + x)); }

// ---------------------------------------------------------------------------
__global__ __launch_bounds__(NTH, 2) void lstm_kernel(
    const float* __restrict__ z,
    const float* __restrict__ Wih, const float* __restrict__ Whh,
    const float* __restrict__ bih, const float* __restrict__ bhh,
    const float* __restrict__ Ws,  const float* __restrict__ bs,
    const float* __restrict__ Wp,  const float* __restrict__ bp,
    unsigned* __restrict__ hb16, float* __restrict__ out)
{
    const int tid  = threadIdx.x;
    const int wv   = tid >> 6;
    const int lane = tid & 63;
    const int l    = blockIdx.x >> 6;          // layer / group
    const int gb   = blockIdx.x & 63;          // block-in-group
    const int uA   = (gb << 4) + (wv << 1);    // wave's first unit

    __shared__ __align__(16) uint4 vh4[2][256]; // dbuf: [part1 128 | part2 128]
    __shared__ unsigned hout[4];               // waves 0-3 pairs (SENT-gated)

    // ---- weights -> registers (fp32 -> f16), chunk-aligned layout --------
    // lane's dot coverage: chunks {lane, 64+lane} of each part
    //   k0-3:  Whh cols 8*lane   .. +7      k4-7:  Whh cols 512+8*lane .. +7
    //   k8-11: Wih cols 8*lane   .. +7      k12-15:Wih cols 512+8*lane .. +7
    h2 w[8][16];
    #pragma unroll
    for (int r = 0; r < 8; ++r) {
        const int u = uA + (r >> 2);
        const int g = r & 3;
        const size_t row = ((size_t)((l << 12) + (g << 10) + u)) << 10;
        const float4* pa = (const float4*)(Whh + row + (lane << 3));
        const float4* pb = (const float4*)(Whh + row + 512 + (lane << 3));
        const float4* pc = (const float4*)(Wih + row + (lane << 3));
        const float4* pd = (const float4*)(Wih + row + 512 + (lane << 3));
        float4 f;
        f = pa[0]; w[r][0]  = mkh2(f.x, f.y); w[r][1]  = mkh2(f.z, f.w);
        f = pa[1]; w[r][2]  = mkh2(f.x, f.y); w[r][3]  = mkh2(f.z, f.w);
        f = pb[0]; w[r][4]  = mkh2(f.x, f.y); w[r][5]  = mkh2(f.z, f.w);
        f = pb[1]; w[r][6]  = mkh2(f.x, f.y); w[r][7]  = mkh2(f.z, f.w);
        f = pc[0]; w[r][8]  = mkh2(f.x, f.y); w[r][9]  = mkh2(f.z, f.w);
        f = pc[1]; w[r][10] = mkh2(f.x, f.y); w[r][11] = mkh2(f.z, f.w);
        f = pd[0]; w[r][12] = mkh2(f.x, f.y); w[r][13] = mkh2(f.z, f.w);
        f = pd[1]; w[r][14] = mkh2(f.x, f.y); w[r][15] = mkh2(f.z, f.w);
    }

    float bA[4], bB[4];
    #pragma unroll
    for (int g = 0; g < 4; ++g) {
        const int iA = (l << 12) + (g << 10) + uA;
        bA[g] = bih[iA] + bhh[iA];
        bB[g] = bih[iA + 1] + bhh[iA + 1];
    }

    // ---- head role (wave 6) ----------------------------------------------
    const bool role_states = (l == 0 && wv == 6);
    const bool role_probs  = (l == 1 && gb == 0 && wv == 6);
    float hw0[16], hw1[16], hb0 = 0.f, hb1 = 0.f;
    if (role_states) {
        #pragma unroll
        for (int k = 0; k < 16; ++k) hw0[k] = Ws[(gb << 10) + (lane << 4) + k];
        hb0 = bs[gb];
    } else if (role_probs) {
        #pragma unroll
        for (int k = 0; k < 16; ++k) {
            hw0[k] = Wp[(lane << 4) + k];
            hw1[k] = Wp[1024 + (lane << 4) + k];
        }
        hb0 = bp[0]; hb1 = bp[1];
    }
    int th = 0;

    float cstA = 0.f, cstB = 0.f;

    // hout sentinel init (ordered before first writes by barrier of t=0)
    if (tid < 4) hout[tid] = SENT;

    #pragma unroll 1
    for (int t = 0; t < TT; ++t) {
        const bool full = (l > 0) || (t == 0);
        const int rb = t & 1;
        const int rep = (gb + wv) & (NREP - 1);

        // ---- staging (waves 0-3; they never global-store) ----
        if (wv < 2) {                              // part1: h_l(t-1)
            const int c = (wv << 6) + lane;
            if (t == 0) vh4[0][c] = make_uint4(0, 0, 0, 0);
            else {
                const uint4* slab = (const uint4*)(hb16 + (size_t)((l * TT + t - 1) * NREP + rep) * SLAB_U32);
                vh4[rb][c] = poll16(slab + c);
            }
        } else if (wv < 4) {                       // part2: h_{l-1}(t) or z
            const int c = ((wv - 2) << 6) + lane;
            if (l > 0) {
                const uint4* slab = (const uint4*)(hb16 + (size_t)(((l - 1) * TT + t) * NREP + rep) * SLAB_U32);
                vh4[rb][128 + c] = poll16(slab + c);
            } else if (t == 0) {
                const float4 f0 = *(const float4*)(z + (c << 3));
                const float4 f1 = *(const float4*)(z + (c << 3) + 4);
                vh4[0][128 + c] = make_uint4(pack2(f0.x, f0.y), pack2(f0.z, f0.w),
                                             pack2(f1.x, f1.y), pack2(f1.z, f1.w));
            }
        }
        __syncthreads();                           // the ONLY barrier per step

        // ---- dot: 8 gate rows per wave, 4x ds_read_b128 ----
        float acc[8] = {0.f, 0.f, 0.f, 0.f, 0.f, 0.f, 0.f, 0.f};
        {
            const uint4 A1 = vh4[rb][lane];
            const uint4 A2 = vh4[rb][64 + lane];
            const unsigned a8[8] = {A1.x, A1.y, A1.z, A1.w, A2.x, A2.y, A2.z, A2.w};
            #pragma unroll
            for (int k = 0; k < 8; ++k) {
                const h2 v2 = as_h2(a8[k]);
                #pragma unroll
                for (int r = 0; r < 8; ++r) acc[r] = fdot2(w[r][k], v2, acc[r]);
            }
            if (full) {
                const uint4 B1 = vh4[rb][128 + lane];
                const uint4 B2 = vh4[rb][192 + lane];
                const unsigned b8[8] = {B1.x, B1.y, B1.z, B1.w, B2.x, B2.y, B2.z, B2.w};
                #pragma unroll
                for (int k = 0; k < 8; ++k) {
                    const h2 v2 = as_h2(b8[k]);
                    #pragma unroll
                    for (int r = 0; r < 8; ++r) acc[r] = fdot2(w[r][8 + k], v2, acc[r]);
                }
            }
        }

        // ---- DPP reduce (VALU pipe) -> uniform gate sums ----
        float tot[8];
        #pragma unroll
        for (int r = 0; r < 8; ++r) tot[r] = wave_sum(acc[r]);

        // ---- uniform nonlinearity on all lanes ----
        cstA = fmaf(sigm(tot[1] + bA[1]), cstA, sigm(tot[0] + bA[0]) * tanh_f(tot[2] + bA[2]));
        cstB = fmaf(sigm(tot[5] + bB[1]), cstB, sigm(tot[4] + bB[0]) * tanh_f(tot[6] + bB[2]));
        const float hA = sigm(tot[3] + bA[3]) * tanh_f(cstA);
        const float hB = sigm(tot[7] + bB[3]) * tanh_f(cstB);
        const unsigned val = pack2(hA, hB);

        if (wv < 4) {
            // ---- hand own pair to buddy publisher (wave wv+4) ----
            if (lane == 0) ((volatile unsigned*)hout)[wv] = val;
        } else {
            // ---- buddy-pair publish: spin on buddy's pair (LDS, fast),
            // then ONE 16-lane scatter store: 8 replicas x {own, buddy}.
            // Gates on max-of-2 waves, not R10's max-of-8 + relay.
            volatile unsigned* vho = (volatile unsigned*)hout;
            unsigned bv = vho[wv - 4];
            while (bv == SENT) { bv = vho[wv - 4]; }
            if (lane == 0) vho[wv - 4] = SENT;     // reset for t+1 (ordered by next barrier)
            if (lane < 16) {
                const unsigned sval = (lane < 8) ? val : bv;
                const int dw = (lane < 8) ? wv : (wv - 4);
                unsigned* addr = hb16 + (size_t)(l * TT + t) * NREP * SLAB_U32
                               + (size_t)(lane & 7) * SLAB_U32 + (gb << 3) + dw;
                store4_bypass(addr, sval);
            }
        }

        // ---- head: non-blocking single-shot try at lag 3 (1 fused RT) ----
        if ((role_states || role_probs) && th < TT && th <= t - 3) {
            const int hrep = (gb + th) & (NREP - 1);
            const uint4* slab3 = (const uint4*)(hb16 + (size_t)((3 * TT + th) * NREP + hrep) * SLAB_U32);
            uint4 r0, r1;
            load32_bypass2(slab3 + (lane << 1), slab3 + (lane << 1) + 1, r0, r1);
            const bool ok = !(stale(r0) | stale(r1));
            if (__ballot(ok) == ~0ull) {
                const unsigned u8[8] = {r0.x, r0.y, r0.z, r0.w, r1.x, r1.y, r1.z, r1.w};
                if (role_states) {
                    float a = 0.f;
                    #pragma unroll
                    for (int j = 0; j < 8; ++j) {
                        const h2 p = as_h2(u8[j]);
                        a = fmaf(hw0[2 * j], (float)p.x, a);
                        a = fmaf(hw0[2 * j + 1], (float)p.y, a);
                    }
                    const float tots = wave_sum(a);
                    if (lane == 0) out[th * 64 + gb] = tots + hb0;
                } else {
                    float a0 = 0.f, a1 = 0.f;
                    #pragma unroll
                    for (int j = 0; j < 8; ++j) {
                        const h2 p = as_h2(u8[j]);
                        a0 = fmaf(hw0[2 * j], (float)p.x, a0); a0 = fmaf(hw0[2 * j + 1], (float)p.y, a0);
                        a1 = fmaf(hw1[2 * j], (float)p.x, a1); a1 = fmaf(hw1[2 * j + 1], (float)p.y, a1);
                    }
                    const float t0 = wave_sum(a0), t1 = wave_sum(a1);
                    if (lane == 0) {
                        float p0, p1;
                        if (th == TT - 1) { p0 = 0.f; p1 = 1.f; }
                        else {
                            const float l0 = t0 + hb0 + 1.0f;   // P_BIAS
                            const float l1 = t1 + hb1;
                            const float m  = fmaxf(l0, l1);
                            const float e0 = expf(l0 - m), e1 = expf(l1 - m);
                            const float inv = 1.f / (e0 + e1);
                            p0 = e0 * inv; p1 = e1 * inv;
                        }
                        out[OUT_PROBS + 2 * th]     = p0;
                        out[OUT_PROBS + 2 * th + 1] = p1;
                        out[OUT_SAMP + th] = (th == TT - 1) ? 1.0f : 0.0f;
                    }
                }
                ++th;
            }
        }
    }

    // ---- head drain (blocking) ----
    if (role_states || role_probs) {
        while (th < TT) {
            const int hrep = (gb + th) & (NREP - 1);
            const uint4* slab3 = (const uint4*)(hb16 + (size_t)((3 * TT + th) * NREP + hrep) * SLAB_U32);
            uint4 r0, r1;
            for (;;) {
                load32_bypass2(slab3 + (lane << 1), slab3 + (lane << 1) + 1, r0, r1);
                if (!(stale(r0) | stale(r1))) break;
                __builtin_amdgcn_s_sleep(1);
            }
            const unsigned u8[8] = {r0.x, r0.y, r0.z, r0.w, r1.x, r1.y, r1.z, r1.w};
            if (role_states) {
                float a = 0.f;
                #pragma unroll
                for (int j = 0; j < 8; ++j) {
                    const h2 p = as_h2(u8[j]);
                    a = fmaf(hw0[2 * j], (float)p.x, a);
                    a = fmaf(hw0[2 * j + 1], (float)p.y, a);
                }
                const float tots = wave_sum(a);
                if (lane == 0) out[th * 64 + gb] = tots + hb0;
            } else {
                float a0 = 0.f, a1 = 0.f;
                #pragma unroll
                for (int j = 0; j < 8; ++j) {
                    const h2 p = as_h2(u8[j]);
                    a0 = fmaf(hw0[2 * j], (float)p.x, a0); a0 = fmaf(hw0[2 * j + 1], (float)p.y, a0);
                    a1 = fmaf(hw1[2 * j], (float)p.x, a1); a1 = fmaf(hw1[2 * j + 1], (float)p.y, a1);
                }
                const float t0 = wave_sum(a0), t1 = wave_sum(a1);
                if (lane == 0) {
                    float p0, p1;
                    if (th == TT - 1) { p0 = 0.f; p1 = 1.f; }
                    else {
                        const float l0 = t0 + hb0 + 1.0f;
                        const float l1 = t1 + hb1;
                        const float m  = fmaxf(l0, l1);
                        const float e0 = expf(l0 - m), e1 = expf(l1 - m);
                        const float inv = 1.f / (e0 + e1);
                        p0 = e0 * inv; p1 = e1 * inv;
                    }
                    out[OUT_PROBS + 2 * th]     = p0;
                    out[OUT_PROBS + 2 * th + 1] = p1;
                    out[OUT_SAMP + th] = (th == TT - 1) ? 1.0f : 0.0f;
                }
            }
            ++th;
        }
    }
}

// ---------------------------------------------------------------------------
extern "C" void kernel_launch(void* const* d_in, const int* in_sizes, int n_in,
                              void* d_out, int out_size, void* d_ws, size_t ws_size,
                              hipStream_t stream)
{
    const float* z   = (const float*)d_in[0];
    const float* Wih = (const float*)d_in[1];
    const float* Whh = (const float*)d_in[2];
    const float* bih = (const float*)d_in[3];
    const float* bhh = (const float*)d_in[4];
    const float* Ws  = (const float*)d_in[5];
    const float* bs  = (const float*)d_in[6];
    const float* Wp  = (const float*)d_in[7];
    const float* bp  = (const float*)d_in[8];
    float* out = (float*)d_out;

    unsigned* hb16 = (unsigned*)d_ws;

    // sentinel-init replicas (ws is re-poisoned before every timed call)
    hipMemsetAsync(hb16, 0xFF, HB16_BYTES, stream);
    lstm_kernel<<<NBLK, NTH, 0, stream>>>(z, Wih, Whh, bih, bhh,
                                          Ws, bs, Wp, bp, hb16, out);
}

// Round 7
// 494.472 us; speedup vs baseline: 1.1135x; 1.1135x over previous
//
#include <hip/hip_runtime.h>

// ---------------------------------------------------------------------------
// PrimitiveDecoder: 4-layer LSTM (NH=1024), T=101 steps, tiny head.
//
// Round-12 = R10 (measured best: 349us dispatch) + two serial-chain
// shorteners, with R10's publish path byte-identical (R11 lesson: the
// single-writer 64-lane coalesced scatter is load-bearing; buddy-split
// publish inflated WRITE 39->56MB and regressed +105us).
//  1. SINGLE barrier per step via double-buffered vh4[2][256]:
//     iter t = { stage(t)->vh4[t&1] (waves 0-3) || head-try (wave 6);
//     barrier; dot(vh4[t&1]); reduce; nonlin; hout; wave7 publish }.
//     Ordering: staging(t+2) overwrites buf[t&1] only after barrier(t+1)
//     which follows all compute(t) reads; hout reset (wave7, pre-barrier)
//     vs hout writes (post-barrier) ordered by the same barrier.
//  2. Head-try hoisted to TOP of iteration: wave6's vmcnt(0) RT runs
//     concurrent with staging waves' poll spin (which gates the barrier
//     anyway) instead of adding ~1 RT between hout-write and barrier2 on
//     every head block (they do strictly more work -> likely stragglers).
// Everything else == R10: poll16 protocol, NREP=8 replicas, lag-3 head,
// fused 1-RT head load, __expf nonlinearity, wave7 hout[8] relay publish.
// Ledger: protocol restructures regress (R7/R8/R9/R11); chain shortening
// wins (R10 -57us). Both deltas here are chain shorteners.
// ---------------------------------------------------------------------------

#define TT    101
#define NBLK  256
#define NTH   512
#define NREP  8
#define SLAB_U32 512                               // 1024 f16 per replica
#define HB16_BYTES (4 * TT * NREP * SLAB_U32 * 4)  // 6,615,040 B
#define OUT_PROBS 6464
#define OUT_SAMP  6666
#define SENT 0xFFFFFFFFu

typedef _Float16 h2 __attribute__((ext_vector_type(2)));

__device__ __forceinline__ h2 mkh2(float a, float b) {
    h2 r; r.x = (_Float16)a; r.y = (_Float16)b; return r;
}
__device__ __forceinline__ unsigned pack2(float a, float b) {
    return __builtin_bit_cast(unsigned, mkh2(a, b));
}
__device__ __forceinline__ h2 as_h2(unsigned u) { return __builtin_bit_cast(h2, u); }

#if __has_builtin(__builtin_amdgcn_fdot2)
__device__ __forceinline__ float fdot2(h2 a, h2 b, float c) {
    return __builtin_amdgcn_fdot2(a, b, c, false);
}
#else
__device__ __forceinline__ float fdot2(h2 a, h2 b, float c) {
    return fmaf((float)a.x, (float)b.x, fmaf((float)a.y, (float)b.y, c));
}
#endif

// 16B cache-bypass load (coherent); waitcnt inside so result regs valid.
__device__ __forceinline__ uint4 load16_bypass(const uint4* p) {
    uint4 r;
    asm volatile("global_load_dwordx4 %0, %1, off sc0 sc1\n\ts_waitcnt vmcnt(0)"
                 : "=v"(r) : "v"(p) : "memory");
    return r;
}
__device__ __forceinline__ void store4_bypass(unsigned* p, unsigned v) {
    asm volatile("global_store_dword %0, %1, off sc0 sc1" :: "v"(p), "v"(v) : "memory");
}
// Two 16B cache-bypass loads back-to-back, ONE vmcnt(0): 1 RT not 2.
__device__ __forceinline__ void load32_bypass2(const uint4* p0, const uint4* p1,
                                               uint4& r0, uint4& r1) {
    asm volatile("global_load_dwordx4 %0, %2, off sc0 sc1\n\t"
                 "global_load_dwordx4 %1, %3, off sc0 sc1\n\t"
                 "s_waitcnt vmcnt(0)"
                 : "=&v"(r0), "=&v"(r1) : "v"(p0), "v"(p1) : "memory");
}
// R5's proven serial poll: load, check, sleep-retry.
__device__ __forceinline__ uint4 poll16(const uint4* p) {
    uint4 r = load16_bypass(p);
    while (r.x == SENT || r.y == SENT || r.z == SENT || r.w == SENT) {
        __builtin_amdgcn_s_sleep(1);
        r = load16_bypass(p);
    }
    return r;
}
__device__ __forceinline__ bool stale(const uint4& u) {
    return (u.x == SENT) | (u.y == SENT) | (u.z == SENT) | (u.w == SENT);
}

// rocPRIM-style full-wave (64) sum via DPP; total broadcast via readlane(63).
__device__ __forceinline__ float wave_sum(float x) {
    int v;
    v = __builtin_amdgcn_update_dpp(0, __builtin_bit_cast(int, x), 0x111, 0xf, 0xf, false);
    x += __builtin_bit_cast(float, v);                                  // row_shr:1
    v = __builtin_amdgcn_update_dpp(0, __builtin_bit_cast(int, x), 0x112, 0xf, 0xf, false);
    x += __builtin_bit_cast(float, v);                                  // row_shr:2
    v = __builtin_amdgcn_update_dpp(0, __builtin_bit_cast(int, x), 0x114, 0xf, 0xe, false);
    x += __builtin_bit_cast(float, v);                                  // row_shr:4
    v = __builtin_amdgcn_update_dpp(0, __builtin_bit_cast(int, x), 0x118, 0xf, 0xc, false);
    x += __builtin_bit_cast(float, v);                                  // row_shr:8
    v = __builtin_amdgcn_update_dpp(0, __builtin_bit_cast(int, x), 0x142, 0xa, 0xf, false);
    x += __builtin_bit_cast(float, v);                                  // row_bcast:15
    v = __builtin_amdgcn_update_dpp(0, __builtin_bit_cast(int, x), 0x143, 0xc, 0xf, false);
    x += __builtin_bit_cast(float, v);                                  // row_bcast:31
    return __builtin_bit_cast(float, __builtin_amdgcn_readlane(__builtin_bit_cast(int, x), 63));
}

// fast transcendentals (v_exp_f32-based); validated R7-R11: absmax equal.
__device__ __forceinline__ float sigm(float x)   { return 1.f / (1.f + __expf(-x)); }
__device__ __forceinline__ float tanh_f(float x) { return 1.f - 2.f / (1.f + __expf(x + x)); }

// ---------------------------------------------------------------------------
__global__ __launch_bounds__(NTH, 2) void lstm_kernel(
    const float* __restrict__ z,
    const float* __restrict__ Wih, const float* __restrict__ Whh,
    const float* __restrict__ bih, const float* __restrict__ bhh,
    const float* __restrict__ Ws,  const float* __restrict__ bs,
    const float* __restrict__ Wp,  const float* __restrict__ bp,
    unsigned* __restrict__ hb16, float* __restrict__ out)
{
    const int tid  = threadIdx.x;
    const int wv   = tid >> 6;
    const int lane = tid & 63;
    const int l    = blockIdx.x >> 6;          // layer / group
    const int gb   = blockIdx.x & 63;          // block-in-group
    const int uA   = (gb << 4) + (wv << 1);    // wave's first unit

    __shared__ __align__(16) uint4 vh4[2][256]; // dbuf: [part1 128 | part2 128]
    __shared__ unsigned hout[8];               // packed h pair per wave (SENT-gated)

    // ---- weights -> registers (fp32 -> f16), chunk-aligned layout --------
    // lane's dot coverage: chunks {lane, 64+lane} of each part
    //   k0-3:  Whh cols 8*lane   .. +7      k4-7:  Whh cols 512+8*lane .. +7
    //   k8-11: Wih cols 8*lane   .. +7      k12-15:Wih cols 512+8*lane .. +7
    h2 w[8][16];
    #pragma unroll
    for (int r = 0; r < 8; ++r) {
        const int u = uA + (r >> 2);
        const int g = r & 3;
        const size_t row = ((size_t)((l << 12) + (g << 10) + u)) << 10;
        const float4* pa = (const float4*)(Whh + row + (lane << 3));
        const float4* pb = (const float4*)(Whh + row + 512 + (lane << 3));
        const float4* pc = (const float4*)(Wih + row + (lane << 3));
        const float4* pd = (const float4*)(Wih + row + 512 + (lane << 3));
        float4 f;
        f = pa[0]; w[r][0]  = mkh2(f.x, f.y); w[r][1]  = mkh2(f.z, f.w);
        f = pa[1]; w[r][2]  = mkh2(f.x, f.y); w[r][3]  = mkh2(f.z, f.w);
        f = pb[0]; w[r][4]  = mkh2(f.x, f.y); w[r][5]  = mkh2(f.z, f.w);
        f = pb[1]; w[r][6]  = mkh2(f.x, f.y); w[r][7]  = mkh2(f.z, f.w);
        f = pc[0]; w[r][8]  = mkh2(f.x, f.y); w[r][9]  = mkh2(f.z, f.w);
        f = pc[1]; w[r][10] = mkh2(f.x, f.y); w[r][11] = mkh2(f.z, f.w);
        f = pd[0]; w[r][12] = mkh2(f.x, f.y); w[r][13] = mkh2(f.z, f.w);
        f = pd[1]; w[r][14] = mkh2(f.x, f.y); w[r][15] = mkh2(f.z, f.w);
    }

    float bA[4], bB[4];
    #pragma unroll
    for (int g = 0; g < 4; ++g) {
        const int iA = (l << 12) + (g << 10) + uA;
        bA[g] = bih[iA] + bhh[iA];
        bB[g] = bih[iA + 1] + bhh[iA + 1];
    }

    // ---- head role (wave 6) ----------------------------------------------
    const bool role_states = (l == 0 && wv == 6);
    const bool role_probs  = (l == 1 && gb == 0 && wv == 6);
    float hw0[16], hw1[16], hb0 = 0.f, hb1 = 0.f;
    if (role_states) {
        #pragma unroll
        for (int k = 0; k < 16; ++k) hw0[k] = Ws[(gb << 10) + (lane << 4) + k];
        hb0 = bs[gb];
    } else if (role_probs) {
        #pragma unroll
        for (int k = 0; k < 16; ++k) {
            hw0[k] = Wp[(lane << 4) + k];
            hw1[k] = Wp[1024 + (lane << 4) + k];
        }
        hb0 = bp[0]; hb1 = bp[1];
    }
    int th = 0;

    float cstA = 0.f, cstB = 0.f;

    // hout sentinel init (ordered before first hout writes by barrier of t=0)
    if (tid < 8) hout[tid] = SENT;

    #pragma unroll 1
    for (int t = 0; t < TT; ++t) {
        const bool full = (l > 0) || (t == 0);
        const int rb = t & 1;
        const int rep = (gb + wv) & (NREP - 1);

        // ---- head-try at TOP (wave 6): RT hides under staging polls ----
        if ((role_states || role_probs) && th < TT && th <= t - 3) {
            const int hrep = (gb + th) & (NREP - 1);
            const uint4* slab3 = (const uint4*)(hb16 + (size_t)((3 * TT + th) * NREP + hrep) * SLAB_U32);
            uint4 r0, r1;
            load32_bypass2(slab3 + (lane << 1), slab3 + (lane << 1) + 1, r0, r1);
            const bool ok = !(stale(r0) | stale(r1));
            if (__ballot(ok) == ~0ull) {
                const unsigned u8[8] = {r0.x, r0.y, r0.z, r0.w, r1.x, r1.y, r1.z, r1.w};
                if (role_states) {
                    float a = 0.f;
                    #pragma unroll
                    for (int j = 0; j < 8; ++j) {
                        const h2 p = as_h2(u8[j]);
                        a = fmaf(hw0[2 * j], (float)p.x, a);
                        a = fmaf(hw0[2 * j + 1], (float)p.y, a);
                    }
                    const float tots = wave_sum(a);
                    if (lane == 0) out[th * 64 + gb] = tots + hb0;
                } else {
                    float a0 = 0.f, a1 = 0.f;
                    #pragma unroll
                    for (int j = 0; j < 8; ++j) {
                        const h2 p = as_h2(u8[j]);
                        a0 = fmaf(hw0[2 * j], (float)p.x, a0); a0 = fmaf(hw0[2 * j + 1], (float)p.y, a0);
                        a1 = fmaf(hw1[2 * j], (float)p.x, a1); a1 = fmaf(hw1[2 * j + 1], (float)p.y, a1);
                    }
                    const float t0 = wave_sum(a0), t1 = wave_sum(a1);
                    if (lane == 0) {
                        float p0, p1;
                        if (th == TT - 1) { p0 = 0.f; p1 = 1.f; }
                        else {
                            const float l0 = t0 + hb0 + 1.0f;   // P_BIAS
                            const float l1 = t1 + hb1;
                            const float m  = fmaxf(l0, l1);
                            const float e0 = expf(l0 - m), e1 = expf(l1 - m);
                            const float inv = 1.f / (e0 + e1);
                            p0 = e0 * inv; p1 = e1 * inv;
                        }
                        out[OUT_PROBS + 2 * th]     = p0;
                        out[OUT_PROBS + 2 * th + 1] = p1;
                        out[OUT_SAMP + th] = (th == TT - 1) ? 1.0f : 0.0f;
                    }
                }
                ++th;
            }
        }

        // ---- staging (waves 0-3; they never global-store) ----
        if (wv < 2) {                              // part1: h_l(t-1)
            const int c = (wv << 6) + lane;
            if (t == 0) vh4[0][c] = make_uint4(0, 0, 0, 0);
            else {
                const uint4* slab = (const uint4*)(hb16 + (size_t)((l * TT + t - 1) * NREP + rep) * SLAB_U32);
                vh4[rb][c] = poll16(slab + c);
            }
        } else if (wv < 4) {                       // part2: h_{l-1}(t) or z
            const int c = ((wv - 2) << 6) + lane;
            if (l > 0) {
                const uint4* slab = (const uint4*)(hb16 + (size_t)(((l - 1) * TT + t) * NREP + rep) * SLAB_U32);
                vh4[rb][128 + c] = poll16(slab + c);
            } else if (t == 0) {
                const float4 f0 = *(const float4*)(z + (c << 3));
                const float4 f1 = *(const float4*)(z + (c << 3) + 4);
                vh4[0][128 + c] = make_uint4(pack2(f0.x, f0.y), pack2(f0.z, f0.w),
                                             pack2(f1.x, f1.y), pack2(f1.z, f1.w));
            }
        }
        __syncthreads();                           // the ONLY barrier per step

        // ---- dot: 8 gate rows per wave, 4x ds_read_b128 ----
        float acc[8] = {0.f, 0.f, 0.f, 0.f, 0.f, 0.f, 0.f, 0.f};
        {
            const uint4 A1 = vh4[rb][lane];
            const uint4 A2 = vh4[rb][64 + lane];
            const unsigned a8[8] = {A1.x, A1.y, A1.z, A1.w, A2.x, A2.y, A2.z, A2.w};
            #pragma unroll
            for (int k = 0; k < 8; ++k) {
                const h2 v2 = as_h2(a8[k]);
                #pragma unroll
                for (int r = 0; r < 8; ++r) acc[r] = fdot2(w[r][k], v2, acc[r]);
            }
            if (full) {
                const uint4 B1 = vh4[rb][128 + lane];
                const uint4 B2 = vh4[rb][192 + lane];
                const unsigned b8[8] = {B1.x, B1.y, B1.z, B1.w, B2.x, B2.y, B2.z, B2.w};
                #pragma unroll
                for (int k = 0; k < 8; ++k) {
                    const h2 v2 = as_h2(b8[k]);
                    #pragma unroll
                    for (int r = 0; r < 8; ++r) acc[r] = fdot2(w[r][8 + k], v2, acc[r]);
                }
            }
        }

        // ---- DPP reduce (VALU pipe) -> uniform gate sums ----
        float tot[8];
        #pragma unroll
        for (int r = 0; r < 8; ++r) tot[r] = wave_sum(acc[r]);

        // ---- uniform nonlinearity on all lanes ----
        cstA = fmaf(sigm(tot[1] + bA[1]), cstA, sigm(tot[0] + bA[0]) * tanh_f(tot[2] + bA[2]));
        cstB = fmaf(sigm(tot[5] + bB[1]), cstB, sigm(tot[4] + bB[0]) * tanh_f(tot[6] + bB[2]));
        const float hA = sigm(tot[3] + bA[3]) * tanh_f(cstA);
        const float hB = sigm(tot[7] + bB[3]) * tanh_f(cstB);
        if (lane == 0) ((volatile unsigned*)hout)[wv] = pack2(hA, hB);

        if (wv == 7) {
            // ---- publish (R10-exact): spin on hout (LDS, fast), ONE 64-lane
            // coalesced scatter store (8 replicas x 8 dwords), reset hout.
            // Store-ack drains lazily; waves 0-3 never global-store.
            volatile unsigned* vho = (volatile unsigned*)hout;
            unsigned v = vho[lane & 7];
            while (v == SENT) { v = vho[lane & 7]; }
            unsigned* addr = hb16 + (size_t)(l * TT + t) * NREP * SLAB_U32
                           + (size_t)(lane >> 3) * SLAB_U32 + (gb << 3) + (lane & 7);
            store4_bypass(addr, v);
            if (lane < 8) vho[lane] = SENT;        // reset for t+1 (ordered by next barrier)
        }
    }

    // ---- head drain (blocking) ----
    if (role_states || role_probs) {
        while (th < TT) {
            const int hrep = (gb + th) & (NREP - 1);
            const uint4* slab3 = (const uint4*)(hb16 + (size_t)((3 * TT + th) * NREP + hrep) * SLAB_U32);
            uint4 r0, r1;
            for (;;) {
                load32_bypass2(slab3 + (lane << 1), slab3 + (lane << 1) + 1, r0, r1);
                if (!(stale(r0) | stale(r1))) break;
                __builtin_amdgcn_s_sleep(1);
            }
            const unsigned u8[8] = {r0.x, r0.y, r0.z, r0.w, r1.x, r1.y, r1.z, r1.w};
            if (role_states) {
                float a = 0.f;
                #pragma unroll
                for (int j = 0; j < 8; ++j) {
                    const h2 p = as_h2(u8[j]);
                    a = fmaf(hw0[2 * j], (float)p.x, a);
                    a = fmaf(hw0[2 * j + 1], (float)p.y, a);
                }
                const float tots = wave_sum(a);
                if (lane == 0) out[th * 64 + gb] = tots + hb0;
            } else {
                float a0 = 0.f, a1 = 0.f;
                #pragma unroll
                for (int j = 0; j < 8; ++j) {
                    const h2 p = as_h2(u8[j]);
                    a0 = fmaf(hw0[2 * j], (float)p.x, a0); a0 = fmaf(hw0[2 * j + 1], (float)p.y, a0);
                    a1 = fmaf(hw1[2 * j], (float)p.x, a1); a1 = fmaf(hw1[2 * j + 1], (float)p.y, a1);
                }
                const float t0 = wave_sum(a0), t1 = wave_sum(a1);
                if (lane == 0) {
                    float p0, p1;
                    if (th == TT - 1) { p0 = 0.f; p1 = 1.f; }
                    else {
                        const float l0 = t0 + hb0 + 1.0f;
                        const float l1 = t1 + hb1;
                        const float m  = fmaxf(l0, l1);
                        const float e0 = expf(l0 - m), e1 = expf(l1 - m);
                        const float inv = 1.f / (e0 + e1);
                        p0 = e0 * inv; p1 = e1 * inv;
                    }
                    out[OUT_PROBS + 2 * th]     = p0;
                    out[OUT_PROBS + 2 * th + 1] = p1;
                    out[OUT_SAMP + th] = (th == TT - 1) ? 1.0f : 0.0f;
                }
            }
            ++th;
        }
    }
}

// ---------------------------------------------------------------------------
extern "C" void kernel_launch(void* const* d_in, const int* in_sizes, int n_in,
                              void* d_out, int out_size, void* d_ws, size_t ws_size,
                              hipStream_t stream)
{
    const float* z   = (const float*)d_in[0];
    const float* Wih = (const float*)d_in[1];
    const float* Whh = (const float*)d_in[2];
    const float* bih = (const float*)d_in[3];
    const float* bhh = (const float*)d_in[4];
    const float* Ws  = (const float*)d_in[5];
    const float* bs  = (const float*)d_in[6];
    const float* Wp  = (const float*)d_in[7];
    const float* bp  = (const float*)d_in[8];
    float* out = (float*)d_out;

    unsigned* hb16 = (unsigned*)d_ws;

    // sentinel-init replicas (ws is re-poisoned before every timed call)
    hipMemsetAsync(hb16, 0xFF, HB16_BYTES, stream);
    lstm_kernel<<<NBLK, NTH, 0, stream>>>(z, Wih, Whh, bih, bhh,
                                          Ws, bs, Wp, bp, hb16, out);
}

// Round 8
// 487.659 us; speedup vs baseline: 1.1291x; 1.0140x over previous
//
#include <hip/hip_runtime.h>

// ---------------------------------------------------------------------------
// PrimitiveDecoder: 4-layer LSTM (NH=1024), T=101 steps, tiny head.
//
// Round-13 = R10 (champion, 349us dispatch) with ONE isolated delta:
// the wave-6 head-try moves from between hout-write and barrier2 to the
// TOP of the iteration (before staging/barrier1).
// Mechanism: in R10 the head-try's fused coherent RT (~0.9us when firing)
// delays barrier2 on all 64 group-0 blocks -- the very producers that the
// part1 recurrence polls -- stretching the pipeline period. At the top of
// the iteration the RT hides under the staging waves' detect spin, which
// gates barrier1 anyway.
// Everything else is R10-exact: two barriers (R12 lesson: barrier2 is a
// free phase-aligner -- staging polls start right after publish, first
// poll lands near visibility; removing it cost +38us and +8.5MB FETCH),
// single vh4[256] buffer, wave7 single-publisher 64-lane coalesced
// scatter (R11 lesson), per-lane NaN-sentinel poll16 (R7/R8/R9 lessons),
// NREP=8 replicas, lag-3 non-blocking head, fused 1-RT head load,
// __expf nonlinearity (absmax-neutral R7-R12).
// ---------------------------------------------------------------------------

#define TT    101
#define NBLK  256
#define NTH   512
#define NREP  8
#define SLAB_U32 512                               // 1024 f16 per replica
#define HB16_BYTES (4 * TT * NREP * SLAB_U32 * 4)  // 6,615,040 B
#define OUT_PROBS 6464
#define OUT_SAMP  6666
#define SENT 0xFFFFFFFFu

typedef _Float16 h2 __attribute__((ext_vector_type(2)));

__device__ __forceinline__ h2 mkh2(float a, float b) {
    h2 r; r.x = (_Float16)a; r.y = (_Float16)b; return r;
}
__device__ __forceinline__ unsigned pack2(float a, float b) {
    return __builtin_bit_cast(unsigned, mkh2(a, b));
}
__device__ __forceinline__ h2 as_h2(unsigned u) { return __builtin_bit_cast(h2, u); }

#if __has_builtin(__builtin_amdgcn_fdot2)
__device__ __forceinline__ float fdot2(h2 a, h2 b, float c) {
    return __builtin_amdgcn_fdot2(a, b, c, false);
}
#else
__device__ __forceinline__ float fdot2(h2 a, h2 b, float c) {
    return fmaf((float)a.x, (float)b.x, fmaf((float)a.y, (float)b.y, c));
}
#endif

// 16B cache-bypass load (coherent); waitcnt inside so result regs valid.
__device__ __forceinline__ uint4 load16_bypass(const uint4* p) {
    uint4 r;
    asm volatile("global_load_dwordx4 %0, %1, off sc0 sc1\n\ts_waitcnt vmcnt(0)"
                 : "=v"(r) : "v"(p) : "memory");
    return r;
}
__device__ __forceinline__ void store4_bypass(unsigned* p, unsigned v) {
    asm volatile("global_store_dword %0, %1, off sc0 sc1" :: "v"(p), "v"(v) : "memory");
}
// Two 16B cache-bypass loads back-to-back, ONE vmcnt(0): 1 RT not 2.
__device__ __forceinline__ void load32_bypass2(const uint4* p0, const uint4* p1,
                                               uint4& r0, uint4& r1) {
    asm volatile("global_load_dwordx4 %0, %2, off sc0 sc1\n\t"
                 "global_load_dwordx4 %1, %3, off sc0 sc1\n\t"
                 "s_waitcnt vmcnt(0)"
                 : "=&v"(r0), "=&v"(r1) : "v"(p0), "v"(p1) : "memory");
}
// R5's proven serial poll: load, check, sleep-retry.
__device__ __forceinline__ uint4 poll16(const uint4* p) {
    uint4 r = load16_bypass(p);
    while (r.x == SENT || r.y == SENT || r.z == SENT || r.w == SENT) {
        __builtin_amdgcn_s_sleep(1);
        r = load16_bypass(p);
    }
    return r;
}
__device__ __forceinline__ bool stale(const uint4& u) {
    return (u.x == SENT) | (u.y == SENT) | (u.z == SENT) | (u.w == SENT);
}

// rocPRIM-style full-wave (64) sum via DPP; total broadcast via readlane(63).
__device__ __forceinline__ float wave_sum(float x) {
    int v;
    v = __builtin_amdgcn_update_dpp(0, __builtin_bit_cast(int, x), 0x111, 0xf, 0xf, false);
    x += __builtin_bit_cast(float, v);                                  // row_shr:1
    v = __builtin_amdgcn_update_dpp(0, __builtin_bit_cast(int, x), 0x112, 0xf, 0xf, false);
    x += __builtin_bit_cast(float, v);                                  // row_shr:2
    v = __builtin_amdgcn_update_dpp(0, __builtin_bit_cast(int, x), 0x114, 0xf, 0xe, false);
    x += __builtin_bit_cast(float, v);                                  // row_shr:4
    v = __builtin_amdgcn_update_dpp(0, __builtin_bit_cast(int, x), 0x118, 0xf, 0xc, false);
    x += __builtin_bit_cast(float, v);                                  // row_shr:8
    v = __builtin_amdgcn_update_dpp(0, __builtin_bit_cast(int, x), 0x142, 0xa, 0xf, false);
    x += __builtin_bit_cast(float, v);                                  // row_bcast:15
    v = __builtin_amdgcn_update_dpp(0, __builtin_bit_cast(int, x), 0x143, 0xc, 0xf, false);
    x += __builtin_bit_cast(float, v);                                  // row_bcast:31
    return __builtin_bit_cast(float, __builtin_amdgcn_readlane(__builtin_bit_cast(int, x), 63));
}

// fast transcendentals (v_exp_f32-based); validated R7-R12: absmax equal.
__device__ __forceinline__ float sigm(float x)   { return 1.f / (1.f + __expf(-x)); }
__device__ __forceinline__ float tanh_f(float x) { return 1.f - 2.f / (1.f + __expf(x + x)); }

// ---------------------------------------------------------------------------
__global__ __launch_bounds__(NTH, 2) void lstm_kernel(
    const float* __restrict__ z,
    const float* __restrict__ Wih, const float* __restrict__ Whh,
    const float* __restrict__ bih, const float* __restrict__ bhh,
    const float* __restrict__ Ws,  const float* __restrict__ bs,
    const float* __restrict__ Wp,  const float* __restrict__ bp,
    unsigned* __restrict__ hb16, float* __restrict__ out)
{
    const int tid  = threadIdx.x;
    const int wv   = tid >> 6;
    const int lane = tid & 63;
    const int l    = blockIdx.x >> 6;          // layer / group
    const int gb   = blockIdx.x & 63;          // block-in-group
    const int uA   = (gb << 4) + (wv << 1);    // wave's first unit

    __shared__ __align__(16) uint4 vh4[256];   // 256 chunks: [part1 128 | part2 128]
    __shared__ unsigned hout[8];               // packed h pair per wave (SENT-gated)

    // ---- weights -> registers (fp32 -> f16), chunk-aligned layout --------
    // lane's dot coverage: chunks {lane, 64+lane} of each part
    //   k0-3:  Whh cols 8*lane   .. +7      k4-7:  Whh cols 512+8*lane .. +7
    //   k8-11: Wih cols 8*lane   .. +7      k12-15:Wih cols 512+8*lane .. +7
    h2 w[8][16];
    #pragma unroll
    for (int r = 0; r < 8; ++r) {
        const int u = uA + (r >> 2);
        const int g = r & 3;
        const size_t row = ((size_t)((l << 12) + (g << 10) + u)) << 10;
        const float4* pa = (const float4*)(Whh + row + (lane << 3));
        const float4* pb = (const float4*)(Whh + row + 512 + (lane << 3));
        const float4* pc = (const float4*)(Wih + row + (lane << 3));
        const float4* pd = (const float4*)(Wih + row + 512 + (lane << 3));
        float4 f;
        f = pa[0]; w[r][0]  = mkh2(f.x, f.y); w[r][1]  = mkh2(f.z, f.w);
        f = pa[1]; w[r][2]  = mkh2(f.x, f.y); w[r][3]  = mkh2(f.z, f.w);
        f = pb[0]; w[r][4]  = mkh2(f.x, f.y); w[r][5]  = mkh2(f.z, f.w);
        f = pb[1]; w[r][6]  = mkh2(f.x, f.y); w[r][7]  = mkh2(f.z, f.w);
        f = pc[0]; w[r][8]  = mkh2(f.x, f.y); w[r][9]  = mkh2(f.z, f.w);
        f = pc[1]; w[r][10] = mkh2(f.x, f.y); w[r][11] = mkh2(f.z, f.w);
        f = pd[0]; w[r][12] = mkh2(f.x, f.y); w[r][13] = mkh2(f.z, f.w);
        f = pd[1]; w[r][14] = mkh2(f.x, f.y); w[r][15] = mkh2(f.z, f.w);
    }

    float bA[4], bB[4];
    #pragma unroll
    for (int g = 0; g < 4; ++g) {
        const int iA = (l << 12) + (g << 10) + uA;
        bA[g] = bih[iA] + bhh[iA];
        bB[g] = bih[iA + 1] + bhh[iA + 1];
    }

    // ---- head role (wave 6) ----------------------------------------------
    const bool role_states = (l == 0 && wv == 6);
    const bool role_probs  = (l == 1 && gb == 0 && wv == 6);
    float hw0[16], hw1[16], hb0 = 0.f, hb1 = 0.f;
    if (role_states) {
        #pragma unroll
        for (int k = 0; k < 16; ++k) hw0[k] = Ws[(gb << 10) + (lane << 4) + k];
        hb0 = bs[gb];
    } else if (role_probs) {
        #pragma unroll
        for (int k = 0; k < 16; ++k) {
            hw0[k] = Wp[(lane << 4) + k];
            hw1[k] = Wp[1024 + (lane << 4) + k];
        }
        hb0 = bp[0]; hb1 = bp[1];
    }
    int th = 0;

    float cstA = 0.f, cstB = 0.f;

    // hout sentinel init (wave 0 lanes; ordered vs wave7's first spin by
    // barrier1 of t=0, which wave 0 passes only after this write)
    if (tid < 8) hout[tid] = SENT;

    #pragma unroll 1
    for (int t = 0; t < TT; ++t) {
        const bool full = (l > 0) || (t == 0);
        const int rep = (gb + wv) & (NREP - 1);

        // ---- head-try at TOP (wave 6): its coherent RT hides under the
        // staging waves' detect spin, which gates barrier1 anyway. In R10
        // this sat between hout-write and barrier2 on all 64 group-0
        // blocks (the part1 producers) -- on the pipeline critical path.
        if ((role_states || role_probs) && th < TT && th <= t - 3) {
            const int hrep = (gb + th) & (NREP - 1);
            const uint4* slab3 = (const uint4*)(hb16 + (size_t)((3 * TT + th) * NREP + hrep) * SLAB_U32);
            uint4 r0, r1;
            load32_bypass2(slab3 + (lane << 1), slab3 + (lane << 1) + 1, r0, r1);
            const bool ok = !(stale(r0) | stale(r1));
            if (__ballot(ok) == ~0ull) {
                const unsigned u8[8] = {r0.x, r0.y, r0.z, r0.w, r1.x, r1.y, r1.z, r1.w};
                if (role_states) {
                    float a = 0.f;
                    #pragma unroll
                    for (int j = 0; j < 8; ++j) {
                        const h2 p = as_h2(u8[j]);
                        a = fmaf(hw0[2 * j], (float)p.x, a);
                        a = fmaf(hw0[2 * j + 1], (float)p.y, a);
                    }
                    const float tots = wave_sum(a);
                    if (lane == 0) out[th * 64 + gb] = tots + hb0;
                } else {
                    float a0 = 0.f, a1 = 0.f;
                    #pragma unroll
                    for (int j = 0; j < 8; ++j) {
                        const h2 p = as_h2(u8[j]);
                        a0 = fmaf(hw0[2 * j], (float)p.x, a0); a0 = fmaf(hw0[2 * j + 1], (float)p.y, a0);
                        a1 = fmaf(hw1[2 * j], (float)p.x, a1); a1 = fmaf(hw1[2 * j + 1], (float)p.y, a1);
                    }
                    const float t0 = wave_sum(a0), t1 = wave_sum(a1);
                    if (lane == 0) {
                        float p0, p1;
                        if (th == TT - 1) { p0 = 0.f; p1 = 1.f; }
                        else {
                            const float l0 = t0 + hb0 + 1.0f;   // P_BIAS
                            const float l1 = t1 + hb1;
                            const float m  = fmaxf(l0, l1);
                            const float e0 = expf(l0 - m), e1 = expf(l1 - m);
                            const float inv = 1.f / (e0 + e1);
                            p0 = e0 * inv; p1 = e1 * inv;
                        }
                        out[OUT_PROBS + 2 * th]     = p0;
                        out[OUT_PROBS + 2 * th + 1] = p1;
                        out[OUT_SAMP + th] = (th == TT - 1) ? 1.0f : 0.0f;
                    }
                }
                ++th;
            }
        }

        // ---- staging (waves 0-3; they never global-store) ----
        if (wv < 2) {                              // part1: h_l(t-1)
            const int c = (wv << 6) + lane;
            if (t == 0) vh4[c] = make_uint4(0, 0, 0, 0);
            else {
                const uint4* slab = (const uint4*)(hb16 + (size_t)((l * TT + t - 1) * NREP + rep) * SLAB_U32);
                vh4[c] = poll16(slab + c);
            }
        } else if (wv < 4) {                       // part2: h_{l-1}(t) or z
            const int c = ((wv - 2) << 6) + lane;
            if (l > 0) {
                const uint4* slab = (const uint4*)(hb16 + (size_t)(((l - 1) * TT + t) * NREP + rep) * SLAB_U32);
                vh4[128 + c] = poll16(slab + c);
            } else if (t == 0) {
                const float4 f0 = *(const float4*)(z + (c << 3));
                const float4 f1 = *(const float4*)(z + (c << 3) + 4);
                vh4[128 + c] = make_uint4(pack2(f0.x, f0.y), pack2(f0.z, f0.w),
                                          pack2(f1.x, f1.y), pack2(f1.z, f1.w));
            }
        }
        __syncthreads();                           // barrier1

        // ---- dot: 8 gate rows per wave, 4x ds_read_b128 ----
        float acc[8] = {0.f, 0.f, 0.f, 0.f, 0.f, 0.f, 0.f, 0.f};
        {
            const uint4 A1 = vh4[lane];
            const uint4 A2 = vh4[64 + lane];
            const unsigned a8[8] = {A1.x, A1.y, A1.z, A1.w, A2.x, A2.y, A2.z, A2.w};
            #pragma unroll
            for (int k = 0; k < 8; ++k) {
                const h2 v2 = as_h2(a8[k]);
                #pragma unroll
                for (int r = 0; r < 8; ++r) acc[r] = fdot2(w[r][k], v2, acc[r]);
            }
            if (full) {
                const uint4 B1 = vh4[128 + lane];
                const uint4 B2 = vh4[192 + lane];
                const unsigned b8[8] = {B1.x, B1.y, B1.z, B1.w, B2.x, B2.y, B2.z, B2.w};
                #pragma unroll
                for (int k = 0; k < 8; ++k) {
                    const h2 v2 = as_h2(b8[k]);
                    #pragma unroll
                    for (int r = 0; r < 8; ++r) acc[r] = fdot2(w[r][8 + k], v2, acc[r]);
                }
            }
        }

        // ---- DPP reduce (VALU pipe) -> uniform gate sums ----
        float tot[8];
        #pragma unroll
        for (int r = 0; r < 8; ++r) tot[r] = wave_sum(acc[r]);

        // ---- uniform nonlinearity on all lanes ----
        cstA = fmaf(sigm(tot[1] + bA[1]), cstA, sigm(tot[0] + bA[0]) * tanh_f(tot[2] + bA[2]));
        cstB = fmaf(sigm(tot[5] + bB[1]), cstB, sigm(tot[4] + bB[0]) * tanh_f(tot[6] + bB[2]));
        const float hA = sigm(tot[3] + bA[3]) * tanh_f(cstA);
        const float hB = sigm(tot[7] + bB[3]) * tanh_f(cstB);
        if (lane == 0) ((volatile unsigned*)hout)[wv] = pack2(hA, hB);

        if (wv == 7) {
            // ---- publish BEFORE barrier2 (R10-exact): spin on hout (LDS),
            // ONE 64-lane coalesced scatter store (8 replicas x 8 dwords),
            // reset hout. Store-ack drains lazily; waves 0-3 never
            // global-store.
            volatile unsigned* vho = (volatile unsigned*)hout;
            unsigned v = vho[lane & 7];
            while (v == SENT) { v = vho[lane & 7]; }
            unsigned* addr = hb16 + (size_t)(l * TT + t) * NREP * SLAB_U32
                           + (size_t)(lane >> 3) * SLAB_U32 + (gb << 3) + (lane & 7);
            store4_bypass(addr, v);
            if (lane < 8) vho[lane] = SENT;        // reset for t+1 (ordered by b2+b1)
        }
        __syncthreads();                           // barrier2
    }

    // ---- head drain (blocking) ----
    if (role_states || role_probs) {
        while (th < TT) {
            const int hrep = (gb + th) & (NREP - 1);
            const uint4* slab3 = (const uint4*)(hb16 + (size_t)((3 * TT + th) * NREP + hrep) * SLAB_U32);
            uint4 r0, r1;
            for (;;) {
                load32_bypass2(slab3 + (lane << 1), slab3 + (lane << 1) + 1, r0, r1);
                if (!(stale(r0) | stale(r1))) break;
                __builtin_amdgcn_s_sleep(1);
            }
            const unsigned u8[8] = {r0.x, r0.y, r0.z, r0.w, r1.x, r1.y, r1.z, r1.w};
            if (role_states) {
                float a = 0.f;
                #pragma unroll
                for (int j = 0; j < 8; ++j) {
                    const h2 p = as_h2(u8[j]);
                    a = fmaf(hw0[2 * j], (float)p.x, a);
                    a = fmaf(hw0[2 * j + 1], (float)p.y, a);
                }
                const float tots = wave_sum(a);
                if (lane == 0) out[th * 64 + gb] = tots + hb0;
            } else {
                float a0 = 0.f, a1 = 0.f;
                #pragma unroll
                for (int j = 0; j < 8; ++j) {
                    const h2 p = as_h2(u8[j]);
                    a0 = fmaf(hw0[2 * j], (float)p.x, a0); a0 = fmaf(hw0[2 * j + 1], (float)p.y, a0);
                    a1 = fmaf(hw1[2 * j], (float)p.x, a1); a1 = fmaf(hw1[2 * j + 1], (float)p.y, a1);
                }
                const float t0 = wave_sum(a0), t1 = wave_sum(a1);
                if (lane == 0) {
                    float p0, p1;
                    if (th == TT - 1) { p0 = 0.f; p1 = 1.f; }
                    else {
                        const float l0 = t0 + hb0 + 1.0f;
                        const float l1 = t1 + hb1;
                        const float m  = fmaxf(l0, l1);
                        const float e0 = expf(l0 - m), e1 = expf(l1 - m);
                        const float inv = 1.f / (e0 + e1);
                        p0 = e0 * inv; p1 = e1 * inv;
                    }
                    out[OUT_PROBS + 2 * th]     = p0;
                    out[OUT_PROBS + 2 * th + 1] = p1;
                    out[OUT_SAMP + th] = (th == TT - 1) ? 1.0f : 0.0f;
                }
            }
            ++th;
        }
    }
}

// ---------------------------------------------------------------------------
extern "C" void kernel_launch(void* const* d_in, const int* in_sizes, int n_in,
                              void* d_out, int out_size, void* d_ws, size_t ws_size,
                              hipStream_t stream)
{
    const float* z   = (const float*)d_in[0];
    const float* Wih = (const float*)d_in[1];
    const float* Whh = (const float*)d_in[2];
    const float* bih = (const float*)d_in[3];
    const float* bhh = (const float*)d_in[4];
    const float* Ws  = (const float*)d_in[5];
    const float* bs  = (const float*)d_in[6];
    const float* Wp  = (const float*)d_in[7];
    const float* bp  = (const float*)d_in[8];
    float* out = (float*)d_out;

    unsigned* hb16 = (unsigned*)d_ws;

    // sentinel-init replicas (ws is re-poisoned before every timed call)
    hipMemsetAsync(hb16, 0xFF, HB16_BYTES, stream);
    lstm_kernel<<<NBLK, NTH, 0, stream>>>(z, Wih, Whh, bih, bhh,
                                          Ws, bs, Wp, bp, hb16, out);
}

// Round 10
// 484.312 us; speedup vs baseline: 1.1369x; 1.0069x over previous
//
#include <hip/hip_runtime.h>

// ---------------------------------------------------------------------------
// PrimitiveDecoder: 4-layer LSTM (NH=1024), T=101 steps, tiny head.
//
// Round-15 = R14 resubmitted verbatim (round-9 bench was an infra failure:
// "MI355X container failed twice" -- no compile or run happened).
//
// R14 = R10 byte-exact (champion: 349us dispatch / 463us bench) plus ONE
// micro-delta: a ~512cy pre-delay (s_sleep 8) before the FIRST part1
// staging poll (waves 0-1, t>0 only).
// Mechanism: part1 polls are first-fail-certain -- the producer publishes
// immediately before barrier2, the consumer polls immediately after it,
// but LLC visibility takes ~1000-1500cy. The first 1-2 poll rounds are
// provably futile coherent reads (128 waves x 101 steps), and FETCH/time
// correlation across rounds (R12: +8.5MB <-> +38us) shows futile probe
// traffic congests the LLC path that store-visibility itself rides.
// NOT applied to: part2 polls (producer ran a full period earlier -- often
// instantly ready), head tries, preamble, drain (R7 lesson: never delay a
// possibly-ready check).
// Position of head-try: R10's late position (after hout write) -- R13
// proved the top-of-loop position costs +26us via a larger drain tail.
// Everything else R10-exact: two barriers, single vh4[256], wave7 single-
// publisher 64-lane coalesced scatter, per-lane NaN-sentinel poll16,
// NREP=8, lag-3 head, fused 1-RT head load, __expf nonlinearity.
// ---------------------------------------------------------------------------

#define TT    101
#define NBLK  256
#define NTH   512
#define NREP  8
#define SLAB_U32 512                               // 1024 f16 per replica
#define HB16_BYTES (4 * TT * NREP * SLAB_U32 * 4)  // 6,615,040 B
#define OUT_PROBS 6464
#define OUT_SAMP  6666
#define SENT 0xFFFFFFFFu

typedef _Float16 h2 __attribute__((ext_vector_type(2)));

__device__ __forceinline__ h2 mkh2(float a, float b) {
    h2 r; r.x = (_Float16)a; r.y = (_Float16)b; return r;
}
__device__ __forceinline__ unsigned pack2(float a, float b) {
    return __builtin_bit_cast(unsigned, mkh2(a, b));
}
__device__ __forceinline__ h2 as_h2(unsigned u) { return __builtin_bit_cast(h2, u); }

#if __has_builtin(__builtin_amdgcn_fdot2)
__device__ __forceinline__ float fdot2(h2 a, h2 b, float c) {
    return __builtin_amdgcn_fdot2(a, b, c, false);
}
#else
__device__ __forceinline__ float fdot2(h2 a, h2 b, float c) {
    return fmaf((float)a.x, (float)b.x, fmaf((float)a.y, (float)b.y, c));
}
#endif

// 16B cache-bypass load (coherent); waitcnt inside so result regs valid.
__device__ __forceinline__ uint4 load16_bypass(const uint4* p) {
    uint4 r;
    asm volatile("global_load_dwordx4 %0, %1, off sc0 sc1\n\ts_waitcnt vmcnt(0)"
                 : "=v"(r) : "v"(p) : "memory");
    return r;
}
__device__ __forceinline__ void store4_bypass(unsigned* p, unsigned v) {
    asm volatile("global_store_dword %0, %1, off sc0 sc1" :: "v"(p), "v"(v) : "memory");
}
// Two 16B cache-bypass loads back-to-back, ONE vmcnt(0): 1 RT not 2.
__device__ __forceinline__ void load32_bypass2(const uint4* p0, const uint4* p1,
                                               uint4& r0, uint4& r1) {
    asm volatile("global_load_dwordx4 %0, %2, off sc0 sc1\n\t"
                 "global_load_dwordx4 %1, %3, off sc0 sc1\n\t"
                 "s_waitcnt vmcnt(0)"
                 : "=&v"(r0), "=&v"(r1) : "v"(p0), "v"(p1) : "memory");
}
// R5's proven serial poll: load, check, sleep-retry.
__device__ __forceinline__ uint4 poll16(const uint4* p) {
    uint4 r = load16_bypass(p);
    while (r.x == SENT || r.y == SENT || r.z == SENT || r.w == SENT) {
        __builtin_amdgcn_s_sleep(1);
        r = load16_bypass(p);
    }
    return r;
}
__device__ __forceinline__ bool stale(const uint4& u) {
    return (u.x == SENT) | (u.y == SENT) | (u.z == SENT) | (u.w == SENT);
}

// rocPRIM-style full-wave (64) sum via DPP; total broadcast via readlane(63).
__device__ __forceinline__ float wave_sum(float x) {
    int v;
    v = __builtin_amdgcn_update_dpp(0, __builtin_bit_cast(int, x), 0x111, 0xf, 0xf, false);
    x += __builtin_bit_cast(float, v);                                  // row_shr:1
    v = __builtin_amdgcn_update_dpp(0, __builtin_bit_cast(int, x), 0x112, 0xf, 0xf, false);
    x += __builtin_bit_cast(float, v);                                  // row_shr:2
    v = __builtin_amdgcn_update_dpp(0, __builtin_bit_cast(int, x), 0x114, 0xf, 0xe, false);
    x += __builtin_bit_cast(float, v);                                  // row_shr:4
    v = __builtin_amdgcn_update_dpp(0, __builtin_bit_cast(int, x), 0x118, 0xf, 0xc, false);
    x += __builtin_bit_cast(float, v);                                  // row_shr:8
    v = __builtin_amdgcn_update_dpp(0, __builtin_bit_cast(int, x), 0x142, 0xa, 0xf, false);
    x += __builtin_bit_cast(float, v);                                  // row_bcast:15
    v = __builtin_amdgcn_update_dpp(0, __builtin_bit_cast(int, x), 0x143, 0xc, 0xf, false);
    x += __builtin_bit_cast(float, v);                                  // row_bcast:31
    return __builtin_bit_cast(float, __builtin_amdgcn_readlane(__builtin_bit_cast(int, x), 63));
}

// fast transcendentals (v_exp_f32-based); validated R7-R13: absmax equal.
__device__ __forceinline__ float sigm(float x)   { return 1.f / (1.f + __expf(-x)); }
__device__ __forceinline__ float tanh_f(float x) { return 1.f - 2.f / (1.f + __expf(x + x)); }

// ---------------------------------------------------------------------------
__global__ __launch_bounds__(NTH, 2) void lstm_kernel(
    const float* __restrict__ z,
    const float* __restrict__ Wih, const float* __restrict__ Whh,
    const float* __restrict__ bih, const float* __restrict__ bhh,
    const float* __restrict__ Ws,  const float* __restrict__ bs,
    const float* __restrict__ Wp,  const float* __restrict__ bp,
    unsigned* __restrict__ hb16, float* __restrict__ out)
{
    const int tid  = threadIdx.x;
    const int wv   = tid >> 6;
    const int lane = tid & 63;
    const int l    = blockIdx.x >> 6;          // layer / group
    const int gb   = blockIdx.x & 63;          // block-in-group
    const int uA   = (gb << 4) + (wv << 1);    // wave's first unit

    __shared__ __align__(16) uint4 vh4[256];   // 256 chunks: [part1 128 | part2 128]
    __shared__ unsigned hout[8];               // packed h pair per wave (SENT-gated)

    // ---- weights -> registers (fp32 -> f16), chunk-aligned layout --------
    // lane's dot coverage: chunks {lane, 64+lane} of each part
    //   k0-3:  Whh cols 8*lane   .. +7      k4-7:  Whh cols 512+8*lane .. +7
    //   k8-11: Wih cols 8*lane   .. +7      k12-15:Wih cols 512+8*lane .. +7
    h2 w[8][16];
    #pragma unroll
    for (int r = 0; r < 8; ++r) {
        const int u = uA + (r >> 2);
        const int g = r & 3;
        const size_t row = ((size_t)((l << 12) + (g << 10) + u)) << 10;
        const float4* pa = (const float4*)(Whh + row + (lane << 3));
        const float4* pb = (const float4*)(Whh + row + 512 + (lane << 3));
        const float4* pc = (const float4*)(Wih + row + (lane << 3));
        const float4* pd = (const float4*)(Wih + row + 512 + (lane << 3));
        float4 f;
        f = pa[0]; w[r][0]  = mkh2(f.x, f.y); w[r][1]  = mkh2(f.z, f.w);
        f = pa[1]; w[r][2]  = mkh2(f.x, f.y); w[r][3]  = mkh2(f.z, f.w);
        f = pb[0]; w[r][4]  = mkh2(f.x, f.y); w[r][5]  = mkh2(f.z, f.w);
        f = pb[1]; w[r][6]  = mkh2(f.x, f.y); w[r][7]  = mkh2(f.z, f.w);
        f = pc[0]; w[r][8]  = mkh2(f.x, f.y); w[r][9]  = mkh2(f.z, f.w);
        f = pc[1]; w[r][10] = mkh2(f.x, f.y); w[r][11] = mkh2(f.z, f.w);
        f = pd[0]; w[r][12] = mkh2(f.x, f.y); w[r][13] = mkh2(f.z, f.w);
        f = pd[1]; w[r][14] = mkh2(f.x, f.y); w[r][15] = mkh2(f.z, f.w);
    }

    float bA[4], bB[4];
    #pragma unroll
    for (int g = 0; g < 4; ++g) {
        const int iA = (l << 12) + (g << 10) + uA;
        bA[g] = bih[iA] + bhh[iA];
        bB[g] = bih[iA + 1] + bhh[iA + 1];
    }

    // ---- head role (wave 6) ----------------------------------------------
    const bool role_states = (l == 0 && wv == 6);
    const bool role_probs  = (l == 1 && gb == 0 && wv == 6);
    float hw0[16], hw1[16], hb0 = 0.f, hb1 = 0.f;
    if (role_states) {
        #pragma unroll
        for (int k = 0; k < 16; ++k) hw0[k] = Ws[(gb << 10) + (lane << 4) + k];
        hb0 = bs[gb];
    } else if (role_probs) {
        #pragma unroll
        for (int k = 0; k < 16; ++k) {
            hw0[k] = Wp[(lane << 4) + k];
            hw1[k] = Wp[1024 + (lane << 4) + k];
        }
        hb0 = bp[0]; hb1 = bp[1];
    }
    int th = 0;

    float cstA = 0.f, cstB = 0.f;

    // hout sentinel init (ordered before first hout writes by barrier1 of t=0)
    if (tid < 8) hout[tid] = SENT;

    #pragma unroll 1
    for (int t = 0; t < TT; ++t) {
        const bool full = (l > 0) || (t == 0);
        const int rep = (gb + wv) & (NREP - 1);

        // ---- staging (waves 0-3; they never global-store) ----
        if (wv < 2) {                              // part1: h_l(t-1)
            const int c = (wv << 6) + lane;
            if (t == 0) vh4[c] = make_uint4(0, 0, 0, 0);
            else {
                // First poll is first-fail-certain (producer stored ~100cy
                // ago; visibility ~1000-1500cy). Pre-delay ~512cy to skip
                // 1-2 futile coherent probe rounds -> less LLC contention
                // on the visibility path. Part2/head/drain NOT delayed.
                __builtin_amdgcn_s_sleep(8);
                const uint4* slab = (const uint4*)(hb16 + (size_t)((l * TT + t - 1) * NREP + rep) * SLAB_U32);
                vh4[c] = poll16(slab + c);
            }
        } else if (wv < 4) {                       // part2: h_{l-1}(t) or z
            const int c = ((wv - 2) << 6) + lane;
            if (l > 0) {
                const uint4* slab = (const uint4*)(hb16 + (size_t)(((l - 1) * TT + t) * NREP + rep) * SLAB_U32);
                vh4[128 + c] = poll16(slab + c);
            } else if (t == 0) {
                const float4 f0 = *(const float4*)(z + (c << 3));
                const float4 f1 = *(const float4*)(z + (c << 3) + 4);
                vh4[128 + c] = make_uint4(pack2(f0.x, f0.y), pack2(f0.z, f0.w),
                                          pack2(f1.x, f1.y), pack2(f1.z, f1.w));
            }
        }
        __syncthreads();                           // barrier1

        // ---- dot: 8 gate rows per wave, 4x ds_read_b128 ----
        float acc[8] = {0.f, 0.f, 0.f, 0.f, 0.f, 0.f, 0.f, 0.f};
        {
            const uint4 A1 = vh4[lane];
            const uint4 A2 = vh4[64 + lane];
            const unsigned a8[8] = {A1.x, A1.y, A1.z, A1.w, A2.x, A2.y, A2.z, A2.w};
            #pragma unroll
            for (int k = 0; k < 8; ++k) {
                const h2 v2 = as_h2(a8[k]);
                #pragma unroll
                for (int r = 0; r < 8; ++r) acc[r] = fdot2(w[r][k], v2, acc[r]);
            }
            if (full) {
                const uint4 B1 = vh4[128 + lane];
                const uint4 B2 = vh4[192 + lane];
                const unsigned b8[8] = {B1.x, B1.y, B1.z, B1.w, B2.x, B2.y, B2.z, B2.w};
                #pragma unroll
                for (int k = 0; k < 8; ++k) {
                    const h2 v2 = as_h2(b8[k]);
                    #pragma unroll
                    for (int r = 0; r < 8; ++r) acc[r] = fdot2(w[r][8 + k], v2, acc[r]);
                }
            }
        }

        // ---- DPP reduce (VALU pipe) -> uniform gate sums ----
        float tot[8];
        #pragma unroll
        for (int r = 0; r < 8; ++r) tot[r] = wave_sum(acc[r]);

        // ---- uniform nonlinearity on all lanes ----
        cstA = fmaf(sigm(tot[1] + bA[1]), cstA, sigm(tot[0] + bA[0]) * tanh_f(tot[2] + bA[2]));
        cstB = fmaf(sigm(tot[5] + bB[1]), cstB, sigm(tot[4] + bB[0]) * tanh_f(tot[6] + bB[2]));
        const float hA = sigm(tot[3] + bA[3]) * tanh_f(cstA);
        const float hB = sigm(tot[7] + bB[3]) * tanh_f(cstB);
        if (lane == 0) ((volatile unsigned*)hout)[wv] = pack2(hA, hB);

        if (wv == 7) {
            // ---- publish BEFORE barrier2 (R10-exact): spin on hout (LDS),
            // ONE 64-lane coalesced scatter store (8 replicas x 8 dwords),
            // reset hout. Store-ack drains lazily; waves 0-3 never
            // global-store.
            volatile unsigned* vho = (volatile unsigned*)hout;
            unsigned v = vho[lane & 7];
            while (v == SENT) { v = vho[lane & 7]; }
            unsigned* addr = hb16 + (size_t)(l * TT + t) * NREP * SLAB_U32
                           + (size_t)(lane >> 3) * SLAB_U32 + (gb << 3) + (lane & 7);
            store4_bypass(addr, v);
            if (lane < 8) vho[lane] = SENT;        // reset for t+1 (ordered by b2+b1)
        } else if ((role_states || role_probs) && th < TT && th <= t - 3) {
            // ---- head: non-blocking single-shot try at lag 3 (1 fused RT),
            // R10's LATE position (R13: top-of-loop position costs +26us
            // via a larger post-loop drain tail).
            const int hrep = (gb + th) & (NREP - 1);
            const uint4* slab3 = (const uint4*)(hb16 + (size_t)((3 * TT + th) * NREP + hrep) * SLAB_U32);
            uint4 r0, r1;
            load32_bypass2(slab3 + (lane << 1), slab3 + (lane << 1) + 1, r0, r1);
            const bool ok = !(stale(r0) | stale(r1));
            if (__ballot(ok) == ~0ull) {
                const unsigned u8[8] = {r0.x, r0.y, r0.z, r0.w, r1.x, r1.y, r1.z, r1.w};
                if (role_states) {
                    float a = 0.f;
                    #pragma unroll
                    for (int j = 0; j < 8; ++j) {
                        const h2 p = as_h2(u8[j]);
                        a = fmaf(hw0[2 * j], (float)p.x, a);
                        a = fmaf(hw0[2 * j + 1], (float)p.y, a);
                    }
                    const float tots = wave_sum(a);
                    if (lane == 0) out[th * 64 + gb] = tots + hb0;
                } else {
                    float a0 = 0.f, a1 = 0.f;
                    #pragma unroll
                    for (int j = 0; j < 8; ++j) {
                        const h2 p = as_h2(u8[j]);
                        a0 = fmaf(hw0[2 * j], (float)p.x, a0); a0 = fmaf(hw0[2 * j + 1], (float)p.y, a0);
                        a1 = fmaf(hw1[2 * j], (float)p.x, a1); a1 = fmaf(hw1[2 * j + 1], (float)p.y, a1);
                    }
                    const float t0 = wave_sum(a0), t1 = wave_sum(a1);
                    if (lane == 0) {
                        float p0, p1;
                        if (th == TT - 1) { p0 = 0.f; p1 = 1.f; }
                        else {
                            const float l0 = t0 + hb0 + 1.0f;   // P_BIAS
                            const float l1 = t1 + hb1;
                            const float m  = fmaxf(l0, l1);
                            const float e0 = expf(l0 - m), e1 = expf(l1 - m);
                            const float inv = 1.f / (e0 + e1);
                            p0 = e0 * inv; p1 = e1 * inv;
                        }
                        out[OUT_PROBS + 2 * th]     = p0;
                        out[OUT_PROBS + 2 * th + 1] = p1;
                        out[OUT_SAMP + th] = (th == TT - 1) ? 1.0f : 0.0f;
                    }
                }
                ++th;
            }
        }
        __syncthreads();                           // barrier2
    }

    // ---- head drain (blocking) ----
    if (role_states || role_probs) {
        while (th < TT) {
            const int hrep = (gb + th) & (NREP - 1);
            const uint4* slab3 = (const uint4*)(hb16 + (size_t)((3 * TT + th) * NREP + hrep) * SLAB_U32);
            uint4 r0, r1;
            for (;;) {
                load32_bypass2(slab3 + (lane << 1), slab3 + (lane << 1) + 1, r0, r1);
                if (!(stale(r0) | stale(r1))) break;
                __builtin_amdgcn_s_sleep(1);
            }
            const unsigned u8[8] = {r0.x, r0.y, r0.z, r0.w, r1.x, r1.y, r1.z, r1.w};
            if (role_states) {
                float a = 0.f;
                #pragma unroll
                for (int j = 0; j < 8; ++j) {
                    const h2 p = as_h2(u8[j]);
                    a = fmaf(hw0[2 * j], (float)p.x, a);
                    a = fmaf(hw0[2 * j + 1], (float)p.y, a);
                }
                const float tots = wave_sum(a);
                if (lane == 0) out[th * 64 + gb] = tots + hb0;
            } else {
                float a0 = 0.f, a1 = 0.f;
                #pragma unroll
                for (int j = 0; j < 8; ++j) {
                    const h2 p = as_h2(u8[j]);
                    a0 = fmaf(hw0[2 * j], (float)p.x, a0); a0 = fmaf(hw0[2 * j + 1], (float)p.y, a0);
                    a1 = fmaf(hw1[2 * j], (float)p.x, a1); a1 = fmaf(hw1[2 * j + 1], (float)p.y, a1);
                }
                const float t0 = wave_sum(a0), t1 = wave_sum(a1);
                if (lane == 0) {
                    float p0, p1;
                    if (th == TT - 1) { p0 = 0.f; p1 = 1.f; }
                    else {
                        const float l0 = t0 + hb0 + 1.0f;
                        const float l1 = t1 + hb1;
                        const float m  = fmaxf(l0, l1);
                        const float e0 = expf(l0 - m), e1 = expf(l1 - m);
                        const float inv = 1.f / (e0 + e1);
                        p0 = e0 * inv; p1 = e1 * inv;
                    }
                    out[OUT_PROBS + 2 * th]     = p0;
                    out[OUT_PROBS + 2 * th + 1] = p1;
                    out[OUT_SAMP + th] = (th == TT - 1) ? 1.0f : 0.0f;
                }
            }
            ++th;
        }
    }
}

// ---------------------------------------------------------------------------
extern "C" void kernel_launch(void* const* d_in, const int* in_sizes, int n_in,
                              void* d_out, int out_size, void* d_ws, size_t ws_size,
                              hipStream_t stream)
{
    const float* z   = (const float*)d_in[0];
    const float* Wih = (const float*)d_in[1];
    const float* Whh = (const float*)d_in[2];
    const float* bih = (const float*)d_in[3];
    const float* bhh = (const float*)d_in[4];
    const float* Ws  = (const float*)d_in[5];
    const float* bs  = (const float*)d_in[6];
    const float* Wp  = (const float*)d_in[7];
    const float* bp  = (const float*)d_in[8];
    float* out = (float*)d_out;

    unsigned* hb16 = (unsigned*)d_ws;

    // sentinel-init replicas (ws is re-poisoned before every timed call)
    hipMemsetAsync(hb16, 0xFF, HB16_BYTES, stream);
    lstm_kernel<<<NBLK, NTH, 0, stream>>>(z, Wih, Whh, bih, bhh,
                                          Ws, bs, Wp, bp, hb16, out);
}

// Round 11
// 457.188 us; speedup vs baseline: 1.2043x; 1.0593x over previous
//
#include <hip/hip_runtime.h>

// ---------------------------------------------------------------------------
// PrimitiveDecoder: 4-layer LSTM (NH=1024), T=101 steps, tiny head.
//
// Round-16 = R10 byte-exact resubmission (champion: 349us dispatch /
// 463.5us bench). Restores the best measured kernel as the deliverable.
//
// Why no further deltas: 9 isolated experiments around R10 all regressed --
//   R7 pipelined/scalar polls      +66us  (sleep-before-check, 4x probes)
//   R8 wave-autonomous (no LDS)   +478us  (8x coherent poll traffic)
//   R9 atomic release gate        +155us  (wait-all-64 + atomic hotspot)
//   R11 buddy-pair publish        +105us  (fragmented 32B->4x8B writes)
//   R12 single-barrier dbuf        +38us  (poll phase misalignment)
//   R13 head-try at loop top       +26us  (more failed tries -> drain tail)
//   R14/R15 512cy poll pre-delay   +24us  (visibility < 512cy; first poll
//                                          usually succeeds -- premise false)
// R10's structure is a sharp local optimum in every probed direction:
//   - 2 barriers/step: barrier2 phase-aligns poll start to publish
//   - wave7 single-publisher, ONE 64-lane coalesced scatter (8 rep x 8 dw)
//   - per-lane NaN-sentinel poll16, immediate first poll, s_sleep(1) retry
//   - publish-before-barrier2 via hout[8] LDS sentinel handoff  (R10 win)
//   - late head-try (after hout write), fused 1-RT dual load    (R10 win)
//   - __expf sigm/tanh                                          (R10 win)
// Step budget ~3.1us: ~1us compute chain + ~2us coherent store->LLC->
// detect + max-of-64 producer skew. The 2us part resisted every protocol
// attack; remaining lever (32blk x 32unit geometry, 256 VGPR) carries
// spill risk against unanimous ledger evidence that restructures regress.
// ---------------------------------------------------------------------------

#define TT    101
#define NBLK  256
#define NTH   512
#define NREP  8
#define SLAB_U32 512                               // 1024 f16 per replica
#define HB16_BYTES (4 * TT * NREP * SLAB_U32 * 4)  // 6,615,040 B
#define OUT_PROBS 6464
#define OUT_SAMP  6666
#define SENT 0xFFFFFFFFu

typedef _Float16 h2 __attribute__((ext_vector_type(2)));

__device__ __forceinline__ h2 mkh2(float a, float b) {
    h2 r; r.x = (_Float16)a; r.y = (_Float16)b; return r;
}
__device__ __forceinline__ unsigned pack2(float a, float b) {
    return __builtin_bit_cast(unsigned, mkh2(a, b));
}
__device__ __forceinline__ h2 as_h2(unsigned u) { return __builtin_bit_cast(h2, u); }

#if __has_builtin(__builtin_amdgcn_fdot2)
__device__ __forceinline__ float fdot2(h2 a, h2 b, float c) {
    return __builtin_amdgcn_fdot2(a, b, c, false);
}
#else
__device__ __forceinline__ float fdot2(h2 a, h2 b, float c) {
    return fmaf((float)a.x, (float)b.x, fmaf((float)a.y, (float)b.y, c));
}
#endif

// 16B cache-bypass load (coherent); waitcnt inside so result regs valid.
__device__ __forceinline__ uint4 load16_bypass(const uint4* p) {
    uint4 r;
    asm volatile("global_load_dwordx4 %0, %1, off sc0 sc1\n\ts_waitcnt vmcnt(0)"
                 : "=v"(r) : "v"(p) : "memory");
    return r;
}
__device__ __forceinline__ void store4_bypass(unsigned* p, unsigned v) {
    asm volatile("global_store_dword %0, %1, off sc0 sc1" :: "v"(p), "v"(v) : "memory");
}
// Two 16B cache-bypass loads back-to-back, ONE vmcnt(0): 1 RT not 2.
__device__ __forceinline__ void load32_bypass2(const uint4* p0, const uint4* p1,
                                               uint4& r0, uint4& r1) {
    asm volatile("global_load_dwordx4 %0, %2, off sc0 sc1\n\t"
                 "global_load_dwordx4 %1, %3, off sc0 sc1\n\t"
                 "s_waitcnt vmcnt(0)"
                 : "=&v"(r0), "=&v"(r1) : "v"(p0), "v"(p1) : "memory");
}
// R5's proven serial poll: load, check, sleep-retry.
__device__ __forceinline__ uint4 poll16(const uint4* p) {
    uint4 r = load16_bypass(p);
    while (r.x == SENT || r.y == SENT || r.z == SENT || r.w == SENT) {
        __builtin_amdgcn_s_sleep(1);
        r = load16_bypass(p);
    }
    return r;
}
__device__ __forceinline__ bool stale(const uint4& u) {
    return (u.x == SENT) | (u.y == SENT) | (u.z == SENT) | (u.w == SENT);
}

// rocPRIM-style full-wave (64) sum via DPP; total broadcast via readlane(63).
__device__ __forceinline__ float wave_sum(float x) {
    int v;
    v = __builtin_amdgcn_update_dpp(0, __builtin_bit_cast(int, x), 0x111, 0xf, 0xf, false);
    x += __builtin_bit_cast(float, v);                                  // row_shr:1
    v = __builtin_amdgcn_update_dpp(0, __builtin_bit_cast(int, x), 0x112, 0xf, 0xf, false);
    x += __builtin_bit_cast(float, v);                                  // row_shr:2
    v = __builtin_amdgcn_update_dpp(0, __builtin_bit_cast(int, x), 0x114, 0xf, 0xe, false);
    x += __builtin_bit_cast(float, v);                                  // row_shr:4
    v = __builtin_amdgcn_update_dpp(0, __builtin_bit_cast(int, x), 0x118, 0xf, 0xc, false);
    x += __builtin_bit_cast(float, v);                                  // row_shr:8
    v = __builtin_amdgcn_update_dpp(0, __builtin_bit_cast(int, x), 0x142, 0xa, 0xf, false);
    x += __builtin_bit_cast(float, v);                                  // row_bcast:15
    v = __builtin_amdgcn_update_dpp(0, __builtin_bit_cast(int, x), 0x143, 0xc, 0xf, false);
    x += __builtin_bit_cast(float, v);                                  // row_bcast:31
    return __builtin_bit_cast(float, __builtin_amdgcn_readlane(__builtin_bit_cast(int, x), 63));
}

// fast transcendentals (v_exp_f32-based); validated R7-R15: absmax equal.
__device__ __forceinline__ float sigm(float x)   { return 1.f / (1.f + __expf(-x)); }
__device__ __forceinline__ float tanh_f(float x) { return 1.f - 2.f / (1.f + __expf(x + x)); }

// ---------------------------------------------------------------------------
__global__ __launch_bounds__(NTH, 2) void lstm_kernel(
    const float* __restrict__ z,
    const float* __restrict__ Wih, const float* __restrict__ Whh,
    const float* __restrict__ bih, const float* __restrict__ bhh,
    const float* __restrict__ Ws,  const float* __restrict__ bs,
    const float* __restrict__ Wp,  const float* __restrict__ bp,
    unsigned* __restrict__ hb16, float* __restrict__ out)
{
    const int tid  = threadIdx.x;
    const int wv   = tid >> 6;
    const int lane = tid & 63;
    const int l    = blockIdx.x >> 6;          // layer / group
    const int gb   = blockIdx.x & 63;          // block-in-group
    const int uA   = (gb << 4) + (wv << 1);    // wave's first unit

    __shared__ __align__(16) uint4 vh4[256];   // 256 chunks: [part1 128 | part2 128]
    __shared__ unsigned hout[8];               // packed h pair per wave (SENT-gated)

    // ---- weights -> registers (fp32 -> f16), chunk-aligned layout --------
    // lane's dot coverage: chunks {lane, 64+lane} of each part
    //   k0-3:  Whh cols 8*lane   .. +7      k4-7:  Whh cols 512+8*lane .. +7
    //   k8-11: Wih cols 8*lane   .. +7      k12-15:Wih cols 512+8*lane .. +7
    h2 w[8][16];
    #pragma unroll
    for (int r = 0; r < 8; ++r) {
        const int u = uA + (r >> 2);
        const int g = r & 3;
        const size_t row = ((size_t)((l << 12) + (g << 10) + u)) << 10;
        const float4* pa = (const float4*)(Whh + row + (lane << 3));
        const float4* pb = (const float4*)(Whh + row + 512 + (lane << 3));
        const float4* pc = (const float4*)(Wih + row + (lane << 3));
        const float4* pd = (const float4*)(Wih + row + 512 + (lane << 3));
        float4 f;
        f = pa[0]; w[r][0]  = mkh2(f.x, f.y); w[r][1]  = mkh2(f.z, f.w);
        f = pa[1]; w[r][2]  = mkh2(f.x, f.y); w[r][3]  = mkh2(f.z, f.w);
        f = pb[0]; w[r][4]  = mkh2(f.x, f.y); w[r][5]  = mkh2(f.z, f.w);
        f = pb[1]; w[r][6]  = mkh2(f.x, f.y); w[r][7]  = mkh2(f.z, f.w);
        f = pc[0]; w[r][8]  = mkh2(f.x, f.y); w[r][9]  = mkh2(f.z, f.w);
        f = pc[1]; w[r][10] = mkh2(f.x, f.y); w[r][11] = mkh2(f.z, f.w);
        f = pd[0]; w[r][12] = mkh2(f.x, f.y); w[r][13] = mkh2(f.z, f.w);
        f = pd[1]; w[r][14] = mkh2(f.x, f.y); w[r][15] = mkh2(f.z, f.w);
    }

    float bA[4], bB[4];
    #pragma unroll
    for (int g = 0; g < 4; ++g) {
        const int iA = (l << 12) + (g << 10) + uA;
        bA[g] = bih[iA] + bhh[iA];
        bB[g] = bih[iA + 1] + bhh[iA + 1];
    }

    // ---- head role (wave 6) ----------------------------------------------
    const bool role_states = (l == 0 && wv == 6);
    const bool role_probs  = (l == 1 && gb == 0 && wv == 6);
    float hw0[16], hw1[16], hb0 = 0.f, hb1 = 0.f;
    if (role_states) {
        #pragma unroll
        for (int k = 0; k < 16; ++k) hw0[k] = Ws[(gb << 10) + (lane << 4) + k];
        hb0 = bs[gb];
    } else if (role_probs) {
        #pragma unroll
        for (int k = 0; k < 16; ++k) {
            hw0[k] = Wp[(lane << 4) + k];
            hw1[k] = Wp[1024 + (lane << 4) + k];
        }
        hb0 = bp[0]; hb1 = bp[1];
    }
    int th = 0;

    float cstA = 0.f, cstB = 0.f;

    // hout sentinel init (ordered before first hout writes by barrier1 of t=0)
    if (tid < 8) hout[tid] = SENT;

    #pragma unroll 1
    for (int t = 0; t < TT; ++t) {
        const bool full = (l > 0) || (t == 0);
        const int rep = (gb + wv) & (NREP - 1);

        // ---- staging (waves 0-3; they never global-store) ----
        if (wv < 2) {                              // part1: h_l(t-1)
            const int c = (wv << 6) + lane;
            if (t == 0) vh4[c] = make_uint4(0, 0, 0, 0);
            else {
                const uint4* slab = (const uint4*)(hb16 + (size_t)((l * TT + t - 1) * NREP + rep) * SLAB_U32);
                vh4[c] = poll16(slab + c);
            }
        } else if (wv < 4) {                       // part2: h_{l-1}(t) or z
            const int c = ((wv - 2) << 6) + lane;
            if (l > 0) {
                const uint4* slab = (const uint4*)(hb16 + (size_t)(((l - 1) * TT + t) * NREP + rep) * SLAB_U32);
                vh4[128 + c] = poll16(slab + c);
            } else if (t == 0) {
                const float4 f0 = *(const float4*)(z + (c << 3));
                const float4 f1 = *(const float4*)(z + (c << 3) + 4);
                vh4[128 + c] = make_uint4(pack2(f0.x, f0.y), pack2(f0.z, f0.w),
                                          pack2(f1.x, f1.y), pack2(f1.z, f1.w));
            }
        }
        __syncthreads();                           // barrier1

        // ---- dot: 8 gate rows per wave, 4x ds_read_b128 ----
        float acc[8] = {0.f, 0.f, 0.f, 0.f, 0.f, 0.f, 0.f, 0.f};
        {
            const uint4 A1 = vh4[lane];
            const uint4 A2 = vh4[64 + lane];
            const unsigned a8[8] = {A1.x, A1.y, A1.z, A1.w, A2.x, A2.y, A2.z, A2.w};
            #pragma unroll
            for (int k = 0; k < 8; ++k) {
                const h2 v2 = as_h2(a8[k]);
                #pragma unroll
                for (int r = 0; r < 8; ++r) acc[r] = fdot2(w[r][k], v2, acc[r]);
            }
            if (full) {
                const uint4 B1 = vh4[128 + lane];
                const uint4 B2 = vh4[192 + lane];
                const unsigned b8[8] = {B1.x, B1.y, B1.z, B1.w, B2.x, B2.y, B2.z, B2.w};
                #pragma unroll
                for (int k = 0; k < 8; ++k) {
                    const h2 v2 = as_h2(b8[k]);
                    #pragma unroll
                    for (int r = 0; r < 8; ++r) acc[r] = fdot2(w[r][8 + k], v2, acc[r]);
                }
            }
        }

        // ---- DPP reduce (VALU pipe) -> uniform gate sums ----
        float tot[8];
        #pragma unroll
        for (int r = 0; r < 8; ++r) tot[r] = wave_sum(acc[r]);

        // ---- uniform nonlinearity on all lanes ----
        cstA = fmaf(sigm(tot[1] + bA[1]), cstA, sigm(tot[0] + bA[0]) * tanh_f(tot[2] + bA[2]));
        cstB = fmaf(sigm(tot[5] + bB[1]), cstB, sigm(tot[4] + bB[0]) * tanh_f(tot[6] + bB[2]));
        const float hA = sigm(tot[3] + bA[3]) * tanh_f(cstA);
        const float hB = sigm(tot[7] + bB[3]) * tanh_f(cstB);
        if (lane == 0) ((volatile unsigned*)hout)[wv] = pack2(hA, hB);

        if (wv == 7) {
            // ---- publish BEFORE barrier2: spin on hout (LDS, fast), issue
            // the 64-lane scatter store immediately, reset hout, then join
            // barrier2. Store-ack drains lazily (next iteration's staging
            // polls don't wait on it; waves 0-3 never global-store).
            volatile unsigned* vho = (volatile unsigned*)hout;
            unsigned v = vho[lane & 7];
            while (v == SENT) { v = vho[lane & 7]; }
            unsigned* addr = hb16 + (size_t)(l * TT + t) * NREP * SLAB_U32
                           + (size_t)(lane >> 3) * SLAB_U32 + (gb << 3) + (lane & 7);
            store4_bypass(addr, v);
            if (lane < 8) vho[lane] = SENT;        // reset for t+1 (ordered by b2+b1)
        } else if ((role_states || role_probs) && th < TT && th <= t - 3) {
            // ---- head: non-blocking single-shot try at lag 3 (1 fused RT) ----
            const int hrep = (gb + th) & (NREP - 1);
            const uint4* slab3 = (const uint4*)(hb16 + (size_t)((3 * TT + th) * NREP + hrep) * SLAB_U32);
            uint4 r0, r1;
            load32_bypass2(slab3 + (lane << 1), slab3 + (lane << 1) + 1, r0, r1);
            const bool ok = !(stale(r0) | stale(r1));
            if (__ballot(ok) == ~0ull) {
                const unsigned u8[8] = {r0.x, r0.y, r0.z, r0.w, r1.x, r1.y, r1.z, r1.w};
                if (role_states) {
                    float a = 0.f;
                    #pragma unroll
                    for (int j = 0; j < 8; ++j) {
                        const h2 p = as_h2(u8[j]);
                        a = fmaf(hw0[2 * j], (float)p.x, a);
                        a = fmaf(hw0[2 * j + 1], (float)p.y, a);
                    }
                    const float tots = wave_sum(a);
                    if (lane == 0) out[th * 64 + gb] = tots + hb0;
                } else {
                    float a0 = 0.f, a1 = 0.f;
                    #pragma unroll
                    for (int j = 0; j < 8; ++j) {
                        const h2 p = as_h2(u8[j]);
                        a0 = fmaf(hw0[2 * j], (float)p.x, a0); a0 = fmaf(hw0[2 * j + 1], (float)p.y, a0);
                        a1 = fmaf(hw1[2 * j], (float)p.x, a1); a1 = fmaf(hw1[2 * j + 1], (float)p.y, a1);
                    }
                    const float t0 = wave_sum(a0), t1 = wave_sum(a1);
                    if (lane == 0) {
                        float p0, p1;
                        if (th == TT - 1) { p0 = 0.f; p1 = 1.f; }
                        else {
                            const float l0 = t0 + hb0 + 1.0f;   // P_BIAS
                            const float l1 = t1 + hb1;
                            const float m  = fmaxf(l0, l1);
                            const float e0 = expf(l0 - m), e1 = expf(l1 - m);
                            const float inv = 1.f / (e0 + e1);
                            p0 = e0 * inv; p1 = e1 * inv;
                        }
                        out[OUT_PROBS + 2 * th]     = p0;
                        out[OUT_PROBS + 2 * th + 1] = p1;
                        out[OUT_SAMP + th] = (th == TT - 1) ? 1.0f : 0.0f;
                    }
                }
                ++th;
            }
        }
        __syncthreads();                           // barrier2
    }

    // ---- head drain (blocking) ----
    if (role_states || role_probs) {
        while (th < TT) {
            const int hrep = (gb + th) & (NREP - 1);
            const uint4* slab3 = (const uint4*)(hb16 + (size_t)((3 * TT + th) * NREP + hrep) * SLAB_U32);
            uint4 r0, r1;
            for (;;) {
                load32_bypass2(slab3 + (lane << 1), slab3 + (lane << 1) + 1, r0, r1);
                if (!(stale(r0) | stale(r1))) break;
                __builtin_amdgcn_s_sleep(1);
            }
            const unsigned u8[8] = {r0.x, r0.y, r0.z, r0.w, r1.x, r1.y, r1.z, r1.w};
            if (role_states) {
                float a = 0.f;
                #pragma unroll
                for (int j = 0; j < 8; ++j) {
                    const h2 p = as_h2(u8[j]);
                    a = fmaf(hw0[2 * j], (float)p.x, a);
                    a = fmaf(hw0[2 * j + 1], (float)p.y, a);
                }
                const float tots = wave_sum(a);
                if (lane == 0) out[th * 64 + gb] = tots + hb0;
            } else {
                float a0 = 0.f, a1 = 0.f;
                #pragma unroll
                for (int j = 0; j < 8; ++j) {
                    const h2 p = as_h2(u8[j]);
                    a0 = fmaf(hw0[2 * j], (float)p.x, a0); a0 = fmaf(hw0[2 * j + 1], (float)p.y, a0);
                    a1 = fmaf(hw1[2 * j], (float)p.x, a1); a1 = fmaf(hw1[2 * j + 1], (float)p.y, a1);
                }
                const float t0 = wave_sum(a0), t1 = wave_sum(a1);
                if (lane == 0) {
                    float p0, p1;
                    if (th == TT - 1) { p0 = 0.f; p1 = 1.f; }
                    else {
                        const float l0 = t0 + hb0 + 1.0f;
                        const float l1 = t1 + hb1;
                        const float m  = fmaxf(l0, l1);
                        const float e0 = expf(l0 - m), e1 = expf(l1 - m);
                        const float inv = 1.f / (e0 + e1);
                        p0 = e0 * inv; p1 = e1 * inv;
                    }
                    out[OUT_PROBS + 2 * th]     = p0;
                    out[OUT_PROBS + 2 * th + 1] = p1;
                    out[OUT_SAMP + th] = (th == TT - 1) ? 1.0f : 0.0f;
                }
            }
            ++th;
        }
    }
}

// ---------------------------------------------------------------------------
extern "C" void kernel_launch(void* const* d_in, const int* in_sizes, int n_in,
                              void* d_out, int out_size, void* d_ws, size_t ws_size,
                              hipStream_t stream)
{
    const float* z   = (const float*)d_in[0];
    const float* Wih = (const float*)d_in[1];
    const float* Whh = (const float*)d_in[2];
    const float* bih = (const float*)d_in[3];
    const float* bhh = (const float*)d_in[4];
    const float* Ws  = (const float*)d_in[5];
    const float* bs  = (const float*)d_in[6];
    const float* Wp  = (const float*)d_in[7];
    const float* bp  = (const float*)d_in[8];
    float* out = (float*)d_out;

    unsigned* hb16 = (unsigned*)d_ws;

    // sentinel-init replicas (ws is re-poisoned before every timed call)
    hipMemsetAsync(hb16, 0xFF, HB16_BYTES, stream);
    lstm_kernel<<<NBLK, NTH, 0, stream>>>(z, Wih, Whh, bih, bhh,
                                          Ws, bs, Wp, bp, hb16, out);
}